// Round 1
// baseline (2481.151 us; speedup 1.0000x reference)
//
#include <hip/hip_runtime.h>

// Problem constants
#define BB 2
#define TT 2048
#define CC 1024
#define HH 16
#define KHH 4
#define HDD 64
#define EE 8
#define II 1024
#define NTOK 4096
#define EPSF 1.1920929e-07f

enum { EPI_NONE = 0, EPI_ADD = 1, EPI_RELUSQ = 2 };

// ---------------- RMSNorm: one block per row of 1024 ----------------
__global__ __launch_bounds__(256) void rmsnorm_k(const float* __restrict__ in,
                                                 float* __restrict__ outp) {
  const int rowi = blockIdx.x;
  const int t = threadIdx.x;
  float4 v = ((const float4*)(in + (size_t)rowi * CC))[t];
  float ss = v.x * v.x + v.y * v.y + v.z * v.z + v.w * v.w;
#pragma unroll
  for (int off = 32; off; off >>= 1) ss += __shfl_down(ss, off, 64);
  __shared__ float red[4];
  if ((t & 63) == 0) red[t >> 6] = ss;
  __syncthreads();
  float tot = red[0] + red[1] + red[2] + red[3];
  float sc = rsqrtf(tot * (1.0f / CC) + EPSF);
  float4 o;
  o.x = v.x * sc; o.y = v.y * sc; o.z = v.z * sc; o.w = v.w * sc;
  ((float4*)(outp + (size_t)rowi * CC))[t] = o;
}

// ---------------- Generic dense GEMM: C[M,N] = A[M,K] @ W[N,K]^T ----------------
// grid = (N/64, M/64), 256 threads, 4x4 per thread, BK=16.
template <int EPI>
__global__ __launch_bounds__(256) void gemm_k(const float* __restrict__ A,
                                              const float* __restrict__ W,
                                              float* __restrict__ C,
                                              const float* __restrict__ add,
                                              int N, int K) {
  __shared__ float As[16][68];
  __shared__ float Ws[16][68];
  const int t = threadIdx.x;
  const int bm = blockIdx.y << 6, bn = blockIdx.x << 6;
  const int lrow = t >> 2, lk = (t & 3) << 2;
  const int tm = (t >> 4) << 2, tn = (t & 15) << 2;
  float acc[4][4] = {};
  const float* Ap = A + (size_t)(bm + lrow) * K + lk;
  const float* Wp = W + (size_t)(bn + lrow) * K + lk;
  for (int k0 = 0; k0 < K; k0 += 16) {
    float4 a4 = *(const float4*)(Ap + k0);
    float4 w4 = *(const float4*)(Wp + k0);
    __syncthreads();
    As[lk + 0][lrow] = a4.x; As[lk + 1][lrow] = a4.y;
    As[lk + 2][lrow] = a4.z; As[lk + 3][lrow] = a4.w;
    Ws[lk + 0][lrow] = w4.x; Ws[lk + 1][lrow] = w4.y;
    Ws[lk + 2][lrow] = w4.z; Ws[lk + 3][lrow] = w4.w;
    __syncthreads();
#pragma unroll
    for (int kk = 0; kk < 16; ++kk) {
      float4 av = *(const float4*)&As[kk][tm];
      float4 wv = *(const float4*)&Ws[kk][tn];
      float am[4] = {av.x, av.y, av.z, av.w};
      float wn[4] = {wv.x, wv.y, wv.z, wv.w};
#pragma unroll
      for (int i = 0; i < 4; ++i)
#pragma unroll
        for (int j = 0; j < 4; ++j) acc[i][j] += am[i] * wn[j];
    }
  }
#pragma unroll
  for (int i = 0; i < 4; ++i) {
    size_t off = (size_t)(bm + tm + i) * N + bn + tn;
    float4 vv = make_float4(acc[i][0], acc[i][1], acc[i][2], acc[i][3]);
    if (EPI == EPI_ADD) {
      float4 ad = *(const float4*)(add + off);
      vv.x += ad.x; vv.y += ad.y; vv.z += ad.z; vv.w += ad.w;
    }
    if (EPI == EPI_RELUSQ) {
      vv.x = vv.x > 0.f ? vv.x * vv.x : 0.f;
      vv.y = vv.y > 0.f ? vv.y * vv.y : 0.f;
      vv.z = vv.z > 0.f ? vv.z * vv.z : 0.f;
      vv.w = vv.w > 0.f ? vv.w * vv.w : 0.f;
    }
    *(float4*)(C + off) = vv;
  }
}

// ---------------- value-embedding gate: v += 2*sigmoid(h[:,:32]@gW^T) * ve ----------------
__global__ __launch_bounds__(256) void gate_k(const float* __restrict__ h,
                                              const float* __restrict__ ve,
                                              const float* __restrict__ gW,
                                              float* __restrict__ v) {
  const int tok = blockIdx.x;
  const int t = threadIdx.x;
  const int kh = t >> 6;
  const float* hrow = h + (size_t)tok * CC;
  const float* gw = gW + kh * 32;
  float dot = 0.f;
#pragma unroll
  for (int j = 0; j < 32; ++j) dot += hrow[j] * gw[j];
  float gate = 2.f / (1.f + __expf(-dot));
  size_t idx = (size_t)tok * (KHH * HDD) + t;
  v[idx] += gate * ve[idx];
}

// ---------------- RoPE + per-head RMSNorm for q (16 heads) and k (4 heads) ----------------
__global__ __launch_bounds__(256) void rope_rms_k(float* __restrict__ q,
                                                  float* __restrict__ kb,
                                                  const float* __restrict__ cosb,
                                                  const float* __restrict__ sinb) {
  const int tok = blockIdx.x;
  const int tpos = tok & (TT - 1);
  const int t = threadIdx.x, lane = t & 63, wid = t >> 6;
  const float c = cosb[(tpos << 5) + (lane & 31)];
  const float s = sinb[(tpos << 5) + (lane & 31)];
#pragma unroll
  for (int i = 0; i < 4; ++i) {
    float* p = q + (size_t)tok * CC + (((wid << 2) + i) << 6) + lane;
    float val = *p;
    float other = __shfl_xor(val, 32, 64);
    float r = (lane < 32) ? (val * c + other * s) : (val * c - other * s);
    float ss = r * r;
#pragma unroll
    for (int off = 32; off; off >>= 1) ss += __shfl_xor(ss, off, 64);
    r *= rsqrtf(ss * (1.f / 64.f) + EPSF);
    *p = r;
  }
  {
    float* p = kb + (size_t)tok * (KHH * HDD) + (wid << 6) + lane;
    float val = *p;
    float other = __shfl_xor(val, 32, 64);
    float r = (lane < 32) ? (val * c + other * s) : (val * c - other * s);
    float ss = r * r;
#pragma unroll
    for (int off = 32; off; off >>= 1) ss += __shfl_xor(ss, off, 64);
    r *= rsqrtf(ss * (1.f / 64.f) + EPSF);
    *p = r;
  }
}

// ---------------- flash attention, 64x64 tiles, fp32 ----------------
// grid = (T/64, H, B), 256 threads. 4 threads per q-row (c=t&3), 16 dims each.
__global__ __launch_bounds__(256) void attn_k(const float* __restrict__ q,
                                              const float* __restrict__ kg,
                                              const float* __restrict__ vg,
                                              float* __restrict__ y,
                                              const int* __restrict__ wszp) {
  const int b = blockIdx.z, h = blockIdx.y, qt = blockIdx.x;
  const int kvh = h >> 2;
  const int Wn = *wszp;
  __shared__ float Ks[64][68], Vs[64][68], Ps[64][68];
  const int t = threadIdx.x;
  const int row = t >> 2, c = t & 3;
  const int lr = t >> 2, lc = (t & 3) << 4;
  const int qglob = (qt << 6) + row;
  float qreg[64];
  {
    const float* qp = q + ((size_t)((b << 11) + qglob)) * CC + (h << 6);
#pragma unroll
    for (int ii = 0; ii < 64; ii += 4) {
      float4 f = *(const float4*)(qp + ii);
      qreg[ii] = f.x; qreg[ii + 1] = f.y; qreg[ii + 2] = f.z; qreg[ii + 3] = f.w;
    }
  }
  float m = -INFINITY, l = 0.f;
  float o[16] = {};
  int lo = (qt << 6) - Wn + 1;
  int kt0 = lo > 0 ? (lo >> 6) : 0;
  for (int kt = kt0; kt <= qt; ++kt) {
    __syncthreads();
    {
      const float* kp = kg + (size_t)((b << 11) + (kt << 6) + lr) * (KHH * HDD) + (kvh << 6) + lc;
      const float* vp = vg + (size_t)((b << 11) + (kt << 6) + lr) * (KHH * HDD) + (kvh << 6) + lc;
#pragma unroll
      for (int ii = 0; ii < 16; ii += 4) {
        *(float4*)&Ks[lr][lc + ii] = *(const float4*)(kp + ii);
        *(float4*)&Vs[lr][lc + ii] = *(const float4*)(vp + ii);
      }
    }
    __syncthreads();
    float sv[16];
#pragma unroll
    for (int j = 0; j < 16; ++j) {
      int col = c + (j << 2);
      const float* kr = &Ks[col][0];
      float acc = 0.f;
#pragma unroll
      for (int kk = 0; kk < 64; kk += 4) {
        float4 k4 = *(const float4*)(kr + kk);
        acc += qreg[kk] * k4.x + qreg[kk + 1] * k4.y + qreg[kk + 2] * k4.z + qreg[kk + 3] * k4.w;
      }
      int sg = (kt << 6) + col;
      bool okm = (sg <= qglob) && (sg > qglob - Wn);
      sv[j] = okm ? acc * 0.125f : -INFINITY;
    }
    float mt = sv[0];
#pragma unroll
    for (int j = 1; j < 16; ++j) mt = fmaxf(mt, sv[j]);
    mt = fmaxf(mt, __shfl_xor(mt, 1, 64));
    mt = fmaxf(mt, __shfl_xor(mt, 2, 64));
    float mn = fmaxf(m, mt);
    float scale = (m > -INFINITY) ? __expf(m - mn) : 0.f;
    float rs = 0.f;
#pragma unroll
    for (int j = 0; j < 16; ++j) {
      float p = (sv[j] > -INFINITY) ? __expf(sv[j] - mn) : 0.f;
      rs += p;
      Ps[row][c + (j << 2)] = p;
    }
    rs += __shfl_xor(rs, 1, 64);
    rs += __shfl_xor(rs, 2, 64);
    l = l * scale + rs;
    m = mn;
#pragma unroll
    for (int i = 0; i < 16; ++i) o[i] *= scale;
    __syncthreads();
    for (int s4 = 0; s4 < 64; s4 += 4) {
      float4 p4 = *(const float4*)&Ps[row][s4];
      float pv[4] = {p4.x, p4.y, p4.z, p4.w};
#pragma unroll
      for (int u = 0; u < 4; ++u) {
        const float* vr = &Vs[s4 + u][lc];
#pragma unroll
        for (int i4 = 0; i4 < 16; i4 += 4) {
          float4 v4 = *(const float4*)(vr + i4);
          o[i4] += pv[u] * v4.x; o[i4 + 1] += pv[u] * v4.y;
          o[i4 + 2] += pv[u] * v4.z; o[i4 + 3] += pv[u] * v4.w;
        }
      }
    }
  }
  float inv = (l > 0.f) ? 1.f / l : 0.f;
  float* yp = y + ((size_t)((b << 11) + qglob)) * CC + (h << 6) + lc;
#pragma unroll
  for (int i4 = 0; i4 < 16; i4 += 4) {
    float4 r4;
    r4.x = o[i4] * inv; r4.y = o[i4 + 1] * inv;
    r4.z = o[i4 + 2] * inv; r4.w = o[i4 + 3] * inv;
    *(float4*)(yp + i4) = r4;
  }
}

// ---------------- router: sigmoid logits, top-2, counts ----------------
__global__ __launch_bounds__(256) void router_k(const float* __restrict__ h2,
                                                const float* __restrict__ rW,
                                                const float* __restrict__ bias,
                                                int* __restrict__ topi,
                                                float* __restrict__ topw,
                                                int* __restrict__ counts) {
  const int n = blockIdx.x;
  const int t = threadIdx.x;
  const int e = t >> 5, lane = t & 31;
  const float* hr = h2 + (size_t)n * CC;
  const float* wr = rW + (e << 10);
  float acc = 0.f;
  for (int j = lane; j < CC; j += 32) acc += hr[j] * wr[j];
#pragma unroll
  for (int off = 16; off; off >>= 1) acc += __shfl_xor(acc, off, 64);
  __shared__ float sc[8], sel[8];
  if (lane == 0) {
    float sg = 1.f / (1.f + __expf(-acc));
    sc[e] = sg;
    sel[e] = sg + bias[e];
  }
  __syncthreads();
  if (t == 0) {
    int i1 = 0; float b1 = sel[0];
    for (int j = 1; j < 8; ++j) if (sel[j] > b1) { b1 = sel[j]; i1 = j; }
    int i2 = -1; float b2 = -INFINITY;
    for (int j = 0; j < 8; ++j) if (j != i1 && sel[j] > b2) { b2 = sel[j]; i2 = j; }
    float w1 = sc[i1], w2 = sc[i2];
    float invs = 1.f / (w1 + w2 + 1e-20f);
    topi[n * 2] = i1; topi[n * 2 + 1] = i2;
    topw[n * 2] = w1 * invs; topw[n * 2 + 1] = w2 * invs;
    atomicAdd(&counts[i1], 1);
    atomicAdd(&counts[i2], 1);
  }
}

__global__ void scan_k(const int* __restrict__ counts, int* __restrict__ offsets) {
  if (threadIdx.x == 0 && blockIdx.x == 0) {
    int s = 0;
    for (int e = 0; e < 8; ++e) { offsets[e] = s; s += counts[e]; }
    offsets[8] = s;
  }
}

__global__ __launch_bounds__(256) void scatter_k(const int* __restrict__ topi,
                                                 const float* __restrict__ topw,
                                                 const int* __restrict__ offsets,
                                                 int* __restrict__ counts2,
                                                 int* __restrict__ tok_idx,
                                                 float* __restrict__ tok_w,
                                                 int* __restrict__ pospair) {
  int n = blockIdx.x * 256 + threadIdx.x;
  if (n >= NTOK) return;
  for (int kk = 0; kk < 2; ++kk) {
    int e = topi[n * 2 + kk];
    int slot = atomicAdd(&counts2[e], 1);
    int p = offsets[e] + slot;
    tok_idx[p] = n;
    tok_w[p] = topw[n * 2 + kk];
    pospair[n * 2 + kk] = p;
  }
}

// ---------------- expert fc: he[pair,i] = relu(h2[tok] @ Wfc[e]^T)^2 (gathered) ----------------
__global__ __launch_bounds__(256) void exp_fc_k(const float* __restrict__ h2,
                                                const float* __restrict__ Wfc,
                                                const int* __restrict__ offsets,
                                                const int* __restrict__ counts,
                                                const int* __restrict__ tok_idx,
                                                float* __restrict__ he) {
  const int e = blockIdx.z;
  const int cnt = counts[e];
  const int mt = blockIdx.y << 6;
  if (mt >= cnt) return;
  const int base = offsets[e];
  __shared__ float As[16][68];
  __shared__ float Ws[16][68];
  const int t = threadIdx.x;
  const int bn = blockIdx.x << 6;
  const int lrow = t >> 2, lk = (t & 3) << 2;
  const int tm = (t >> 4) << 2, tn = (t & 15) << 2;
  int r = mt + lrow;
  int token = tok_idx[base + (r < cnt ? r : cnt - 1)];
  const float* Ap = h2 + (size_t)token * CC + lk;
  const float* Wp = Wfc + ((size_t)e << 20) + (size_t)(bn + lrow) * CC + lk;
  float acc[4][4] = {};
  for (int k0 = 0; k0 < CC; k0 += 16) {
    float4 a4 = *(const float4*)(Ap + k0);
    float4 w4 = *(const float4*)(Wp + k0);
    __syncthreads();
    As[lk + 0][lrow] = a4.x; As[lk + 1][lrow] = a4.y;
    As[lk + 2][lrow] = a4.z; As[lk + 3][lrow] = a4.w;
    Ws[lk + 0][lrow] = w4.x; Ws[lk + 1][lrow] = w4.y;
    Ws[lk + 2][lrow] = w4.z; Ws[lk + 3][lrow] = w4.w;
    __syncthreads();
#pragma unroll
    for (int kk = 0; kk < 16; ++kk) {
      float4 av = *(const float4*)&As[kk][tm];
      float4 wv = *(const float4*)&Ws[kk][tn];
      float am[4] = {av.x, av.y, av.z, av.w};
      float wn[4] = {wv.x, wv.y, wv.z, wv.w};
#pragma unroll
      for (int i = 0; i < 4; ++i)
#pragma unroll
        for (int j = 0; j < 4; ++j) acc[i][j] += am[i] * wn[j];
    }
  }
#pragma unroll
  for (int i = 0; i < 4; ++i) {
    int rr = mt + tm + i;
    if (rr < cnt) {
      size_t off = (size_t)(base + rr) * II + bn + tn;
      float4 vv;
      vv.x = acc[i][0] > 0.f ? acc[i][0] * acc[i][0] : 0.f;
      vv.y = acc[i][1] > 0.f ? acc[i][1] * acc[i][1] : 0.f;
      vv.z = acc[i][2] > 0.f ? acc[i][2] * acc[i][2] : 0.f;
      vv.w = acc[i][3] > 0.f ? acc[i][3] * acc[i][3] : 0.f;
      *(float4*)(he + off) = vv;
    }
  }
}

// ---------------- expert proj: pairout[pair,c] = w * (he[pair] @ Wproj[e]^T) ----------------
__global__ __launch_bounds__(256) void exp_proj_k(const float* __restrict__ he,
                                                  const float* __restrict__ Wproj,
                                                  const int* __restrict__ offsets,
                                                  const int* __restrict__ counts,
                                                  const float* __restrict__ tok_w,
                                                  float* __restrict__ pairout) {
  const int e = blockIdx.z;
  const int cnt = counts[e];
  const int mt = blockIdx.y << 6;
  if (mt >= cnt) return;
  const int base = offsets[e];
  __shared__ float As[16][68];
  __shared__ float Ws[16][68];
  const int t = threadIdx.x;
  const int bn = blockIdx.x << 6;
  const int lrow = t >> 2, lk = (t & 3) << 2;
  const int tm = (t >> 4) << 2, tn = (t & 15) << 2;
  int r = mt + lrow;
  int ridx = base + (r < cnt ? r : cnt - 1);
  const float* Ap = he + (size_t)ridx * II + lk;
  const float* Wp = Wproj + ((size_t)e << 20) + (size_t)(bn + lrow) * II + lk;
  float acc[4][4] = {};
  for (int k0 = 0; k0 < II; k0 += 16) {
    float4 a4 = *(const float4*)(Ap + k0);
    float4 w4 = *(const float4*)(Wp + k0);
    __syncthreads();
    As[lk + 0][lrow] = a4.x; As[lk + 1][lrow] = a4.y;
    As[lk + 2][lrow] = a4.z; As[lk + 3][lrow] = a4.w;
    Ws[lk + 0][lrow] = w4.x; Ws[lk + 1][lrow] = w4.y;
    Ws[lk + 2][lrow] = w4.z; Ws[lk + 3][lrow] = w4.w;
    __syncthreads();
#pragma unroll
    for (int kk = 0; kk < 16; ++kk) {
      float4 av = *(const float4*)&As[kk][tm];
      float4 wv = *(const float4*)&Ws[kk][tn];
      float am[4] = {av.x, av.y, av.z, av.w};
      float wn[4] = {wv.x, wv.y, wv.z, wv.w};
#pragma unroll
      for (int i = 0; i < 4; ++i)
#pragma unroll
        for (int j = 0; j < 4; ++j) acc[i][j] += am[i] * wn[j];
    }
  }
#pragma unroll
  for (int i = 0; i < 4; ++i) {
    int rr = mt + tm + i;
    if (rr < cnt) {
      float wgt = tok_w[base + rr];
      size_t off = (size_t)(base + rr) * CC + bn + tn;
      float4 vv = make_float4(acc[i][0] * wgt, acc[i][1] * wgt, acc[i][2] * wgt, acc[i][3] * wgt);
      *(float4*)(pairout + off) = vv;
    }
  }
}

// ---------------- final: out[n] += pairout[p0] + pairout[p1] ----------------
__global__ __launch_bounds__(256) void final_add_k(float* __restrict__ out,
                                                   const float* __restrict__ pairout,
                                                   const int* __restrict__ pospair) {
  int n = blockIdx.x, t = threadIdx.x;
  int p0 = pospair[n * 2], p1 = pospair[n * 2 + 1];
  float4* o = (float4*)(out + (size_t)n * CC);
  const float4* a = (const float4*)(pairout + (size_t)p0 * CC);
  const float4* b4 = (const float4*)(pairout + (size_t)p1 * CC);
  float4 vo = o[t], va = a[t], vb = b4[t];
  vo.x += va.x + vb.x; vo.y += va.y + vb.y;
  vo.z += va.z + vb.z; vo.w += va.w + vb.w;
  o[t] = vo;
}

extern "C" void kernel_launch(void* const* d_in, const int* in_sizes, int n_in,
                              void* d_out, int out_size, void* d_ws, size_t ws_size,
                              hipStream_t stream) {
  const float* x = (const float*)d_in[0];
  const float* ve = (const float*)d_in[1];
  const float* cosb = (const float*)d_in[2];
  const float* sinb = (const float*)d_in[3];
  const float* Wq = (const float*)d_in[4];
  const float* Wk = (const float*)d_in[5];
  const float* Wv = (const float*)d_in[6];
  const float* Wo = (const float*)d_in[7];
  const float* gW = (const float*)d_in[8];
  const float* routerW = (const float*)d_in[9];
  const float* bias = (const float*)d_in[10];
  const float* Wsfc = (const float*)d_in[11];
  const float* Wsproj = (const float*)d_in[12];
  const float* Wefc = (const float*)d_in[13];
  const float* Weproj = (const float*)d_in[14];
  const int* wsz = (const int*)d_in[15];
  float* out = (float*)d_out;
  float* wsf = (float*)d_ws;

  // workspace layout (floats); total ~88.2 MB
  float* h = wsf;                       // 4,194,304
  float* q = wsf + 4194304;             // 4,194,304
  float* kbuf = wsf + 8388608;          // 1,048,576
  float* vbuf = wsf + 9437184;          // 1,048,576
  float* y = wsf + 10485760;            // 4,194,304 (ends 14,680,064)
  float* he = wsf + 4194304;            // 8,388,608 (aliases q/k/v/y-prefix; all dead by then)
  float* x2 = wsf + 14680064;           // 4,194,304
  float* h2 = wsf + 18874368;           // 4,194,304 (ends 23,068,672)
  float* s1 = h;                        // alias (h dead after qkv+gate)
  float* pairout = wsf + 14680064;      // 8,388,608 (aliases x2+h2; both dead by then)
  int* meta = (int*)(wsf + 23068672);
  int* counts = meta;                   // 8
  int* counts2 = meta + 8;              // 8
  int* offsets = meta + 16;             // 9
  int* topi = meta + 32;                // 8192
  float* topw = (float*)(meta + 8224);  // 8192
  int* tok_idx = meta + 16416;          // 8192
  float* tok_w = (float*)(meta + 24608);// 8192
  int* pospair = meta + 32800;          // 8192

  hipMemsetAsync(counts, 0, 16 * sizeof(int), stream);

  // h = rmsnorm(x)
  rmsnorm_k<<<NTOK, 256, 0, stream>>>(x, h);
  // q,k,v projections
  gemm_k<EPI_NONE><<<dim3(16, 64), 256, 0, stream>>>(h, Wq, q, nullptr, 1024, 1024);
  gemm_k<EPI_NONE><<<dim3(4, 64), 256, 0, stream>>>(h, Wk, kbuf, nullptr, 256, 1024);
  gemm_k<EPI_NONE><<<dim3(4, 64), 256, 0, stream>>>(h, Wv, vbuf, nullptr, 256, 1024);
  // v += gate * ve
  gate_k<<<NTOK, 256, 0, stream>>>(h, ve, gW, vbuf);
  // rope + head rmsnorm on q,k
  rope_rms_k<<<NTOK, 256, 0, stream>>>(q, kbuf, cosb, sinb);
  // attention
  attn_k<<<dim3(TT / 64, HH, BB), 256, 0, stream>>>(q, kbuf, vbuf, y, wsz);
  // x2 = x + y @ Wo^T
  gemm_k<EPI_ADD><<<dim3(16, 64), 256, 0, stream>>>(y, Wo, x2, x, 1024, 1024);
  // h2 = rmsnorm(x2)
  rmsnorm_k<<<NTOK, 256, 0, stream>>>(x2, h2);
  // shared expert
  gemm_k<EPI_RELUSQ><<<dim3(16, 64), 256, 0, stream>>>(h2, Wsfc, s1, nullptr, 1024, 1024);
  gemm_k<EPI_ADD><<<dim3(16, 64), 256, 0, stream>>>(s1, Wsproj, out, x2, 1024, 1024);
  // router + bucketing
  router_k<<<NTOK, 256, 0, stream>>>(h2, routerW, bias, topi, topw, counts);
  scan_k<<<1, 64, 0, stream>>>(counts, offsets);
  scatter_k<<<16, 256, 0, stream>>>(topi, topw, offsets, counts2, tok_idx, tok_w, pospair);
  // routed experts (grouped GEMMs, top-2 only)
  exp_fc_k<<<dim3(16, 64, 8), 256, 0, stream>>>(h2, Wefc, offsets, counts, tok_idx, he);
  exp_proj_k<<<dim3(16, 64, 8), 256, 0, stream>>>(he, Weproj, offsets, counts, tok_w, pairout);
  // out += routed
  final_add_k<<<NTOK, 256, 0, stream>>>(out, pairout, pospair);
}

// Round 2
// 1369.320 us; speedup vs baseline: 1.8120x; 1.8120x over previous
//
#include <hip/hip_runtime.h>

// Problem constants
#define BB 2
#define TT 2048
#define CC 1024
#define HH 16
#define KHH 4
#define HDD 64
#define EE 8
#define II 1024
#define NTOK 4096
#define EPSF 1.1920929e-07f

typedef unsigned short u16;
typedef short bf16x8 __attribute__((ext_vector_type(8)));
typedef float f32x4 __attribute__((ext_vector_type(4)));

enum { EPI_NONE = 0, EPI_ADD = 1, EPI_RELUSQ = 2 };

__device__ inline u16 f2b(float f) {
  union { float f; unsigned u; } v; v.f = f;
  unsigned r = v.u + 0x7FFFu + ((v.u >> 16) & 1u);
  return (u16)(r >> 16);
}

// ---------------- RMSNorm: one block per row of 1024 ----------------
__global__ __launch_bounds__(256) void rmsnorm_k(const float* __restrict__ in,
                                                 float* __restrict__ outp) {
  const int rowi = blockIdx.x;
  const int t = threadIdx.x;
  float4 v = ((const float4*)(in + (size_t)rowi * CC))[t];
  float ss = v.x * v.x + v.y * v.y + v.z * v.z + v.w * v.w;
#pragma unroll
  for (int off = 32; off; off >>= 1) ss += __shfl_down(ss, off, 64);
  __shared__ float red[4];
  if ((t & 63) == 0) red[t >> 6] = ss;
  __syncthreads();
  float tot = red[0] + red[1] + red[2] + red[3];
  float sc = rsqrtf(tot * (1.0f / CC) + EPSF);
  float4 o;
  o.x = v.x * sc; o.y = v.y * sc; o.z = v.z * sc; o.w = v.w * sc;
  ((float4*)(outp + (size_t)rowi * CC))[t] = o;
}

// ---------------- Generic dense GEMM: C[M,N] = A[M,K] @ W[N,K]^T ----------------
template <int EPI>
__global__ __launch_bounds__(256) void gemm_k(const float* __restrict__ A,
                                              const float* __restrict__ W,
                                              float* __restrict__ C,
                                              const float* __restrict__ add,
                                              int N, int K) {
  __shared__ float As[16][68];
  __shared__ float Ws[16][68];
  const int t = threadIdx.x;
  const int bm = blockIdx.y << 6, bn = blockIdx.x << 6;
  const int lrow = t >> 2, lk = (t & 3) << 2;
  const int tm = (t >> 4) << 2, tn = (t & 15) << 2;
  float acc[4][4] = {};
  const float* Ap = A + (size_t)(bm + lrow) * K + lk;
  const float* Wp = W + (size_t)(bn + lrow) * K + lk;
  for (int k0 = 0; k0 < K; k0 += 16) {
    float4 a4 = *(const float4*)(Ap + k0);
    float4 w4 = *(const float4*)(Wp + k0);
    __syncthreads();
    As[lk + 0][lrow] = a4.x; As[lk + 1][lrow] = a4.y;
    As[lk + 2][lrow] = a4.z; As[lk + 3][lrow] = a4.w;
    Ws[lk + 0][lrow] = w4.x; Ws[lk + 1][lrow] = w4.y;
    Ws[lk + 2][lrow] = w4.z; Ws[lk + 3][lrow] = w4.w;
    __syncthreads();
#pragma unroll
    for (int kk = 0; kk < 16; ++kk) {
      float4 av = *(const float4*)&As[kk][tm];
      float4 wv = *(const float4*)&Ws[kk][tn];
      float am[4] = {av.x, av.y, av.z, av.w};
      float wn[4] = {wv.x, wv.y, wv.z, wv.w};
#pragma unroll
      for (int i = 0; i < 4; ++i)
#pragma unroll
        for (int j = 0; j < 4; ++j) acc[i][j] += am[i] * wn[j];
    }
  }
#pragma unroll
  for (int i = 0; i < 4; ++i) {
    size_t off = (size_t)(bm + tm + i) * N + bn + tn;
    float4 vv = make_float4(acc[i][0], acc[i][1], acc[i][2], acc[i][3]);
    if (EPI == EPI_ADD) {
      float4 ad = *(const float4*)(add + off);
      vv.x += ad.x; vv.y += ad.y; vv.z += ad.z; vv.w += ad.w;
    }
    if (EPI == EPI_RELUSQ) {
      vv.x = vv.x > 0.f ? vv.x * vv.x : 0.f;
      vv.y = vv.y > 0.f ? vv.y * vv.y : 0.f;
      vv.z = vv.z > 0.f ? vv.z * vv.z : 0.f;
      vv.w = vv.w > 0.f ? vv.w * vv.w : 0.f;
    }
    *(float4*)(C + off) = vv;
  }
}

// ---------------- value-embedding gate: vb = bf16(v + 2*sigmoid(h[:,:32]@gW^T) * ve) ----------------
__global__ __launch_bounds__(256) void gate_k(const float* __restrict__ h,
                                              const float* __restrict__ ve,
                                              const float* __restrict__ gW,
                                              const float* __restrict__ vf,
                                              u16* __restrict__ vbo) {
  const int tok = blockIdx.x;
  const int t = threadIdx.x;
  const int kh = t >> 6;
  const float* hrow = h + (size_t)tok * CC;
  const float* gw = gW + kh * 32;
  float dot = 0.f;
#pragma unroll
  for (int j = 0; j < 32; ++j) dot += hrow[j] * gw[j];
  float gate = 2.f / (1.f + __expf(-dot));
  size_t idx = (size_t)tok * 256 + t;
  vbo[idx] = f2b(vf[idx] + gate * ve[idx]);
}

// ---------------- RoPE + per-head RMSNorm -> bf16 q,k ----------------
__global__ __launch_bounds__(256) void rope_rms_k(const float* __restrict__ q,
                                                  const float* __restrict__ kbf,
                                                  const float* __restrict__ cosb,
                                                  const float* __restrict__ sinb,
                                                  u16* __restrict__ qbo,
                                                  u16* __restrict__ kbo) {
  const int tok = blockIdx.x;
  const int tpos = tok & (TT - 1);
  const int t = threadIdx.x, lane = t & 63, wid = t >> 6;
  const float c = cosb[(tpos << 5) + (lane & 31)];
  const float s = sinb[(tpos << 5) + (lane & 31)];
#pragma unroll
  for (int i = 0; i < 4; ++i) {
    size_t off = (size_t)tok * CC + (((wid << 2) + i) << 6) + lane;
    float val = q[off];
    float other = __shfl_xor(val, 32, 64);
    float r = (lane < 32) ? (val * c + other * s) : (val * c - other * s);
    float ss = r * r;
#pragma unroll
    for (int o2 = 32; o2; o2 >>= 1) ss += __shfl_xor(ss, o2, 64);
    r *= rsqrtf(ss * (1.f / 64.f) + EPSF);
    qbo[off] = f2b(r);
  }
  {
    size_t off = (size_t)tok * 256 + (wid << 6) + lane;
    float val = kbf[off];
    float other = __shfl_xor(val, 32, 64);
    float r = (lane < 32) ? (val * c + other * s) : (val * c - other * s);
    float ss = r * r;
#pragma unroll
    for (int o2 = 32; o2; o2 >>= 1) ss += __shfl_xor(ss, o2, 64);
    r *= rsqrtf(ss * (1.f / 64.f) + EPSF);
    kbo[off] = f2b(r);
  }
}

// ---------------- flash attention, bf16 MFMA 16x16x32, 64x64 tiles ----------------
// grid = (T/64, H, B), 256 threads = 4 waves; wave w owns q-rows [qt*64+16w, +16).
__global__ __launch_bounds__(256) void attn_mfma_k(const u16* __restrict__ qb,
                                                   const u16* __restrict__ kb,
                                                   const u16* __restrict__ vb,
                                                   float* __restrict__ y,
                                                   const int* __restrict__ wszp) {
  const int b = blockIdx.z, h = blockIdx.y, qt = blockIdx.x;
  const int kvh = h >> 2;
  const int Wn = *wszp;
  const int t = threadIdx.x;
  const int lane = t & 63, wave = t >> 6;
  const int l15 = lane & 15, hi = lane >> 4;

  __shared__ u16 Klds[64][72];   // K natural [key][d], 144B rows (16B aligned)
  __shared__ u16 Vt[64][72];     // V transposed [d][key]
  __shared__ u16 Plds[4][16][72];// per-wave P [q][key]

  const int qrow0 = (qt << 6) + (wave << 4);
  bf16x8 aQ0, aQ1;
  {
    const u16* qp = qb + ((size_t)((b << 11) + qrow0 + l15) << 10) + (h << 6) + (hi << 3);
    aQ0 = *(const bf16x8*)qp;
    aQ1 = *(const bf16x8*)(qp + 32);
  }
  f32x4 o[4] = {};
  float mrow[4] = {-INFINITY, -INFINITY, -INFINITY, -INFINITY};
  float lrow[4] = {0.f, 0.f, 0.f, 0.f};
  int lo = (qt << 6) - Wn + 1;
  int kt0 = lo > 0 ? (lo >> 6) : 0;

  for (int kt = kt0; kt <= qt; ++kt) {
    __syncthreads();
    // stage K: 512 chunks of 8 bf16; thread t handles chunks t, t+256
#pragma unroll
    for (int i = 0; i < 2; ++i) {
      int lin = t + (i << 8);
      int r = lin >> 3, c = lin & 7;
      const u16* kp = kb + ((size_t)((b << 11) + (kt << 6) + r) << 8) + (kvh << 6) + (c << 3);
      *(bf16x8*)&Klds[r][c << 3] = *(const bf16x8*)kp;
    }
    // stage V transposed: key = t&63, d0 = (t>>6)*8 (+32 for i=1)
#pragma unroll
    for (int i = 0; i < 2; ++i) {
      int key = t & 63;
      int d0 = ((t >> 6) << 3) + (i << 5);
      const u16* vp = vb + ((size_t)((b << 11) + (kt << 6) + key) << 8) + (kvh << 6) + d0;
      bf16x8 vv = *(const bf16x8*)vp;
#pragma unroll
      for (int j = 0; j < 8; ++j) Vt[d0 + j][key] = (u16)vv[j];
    }
    __syncthreads();

    // QK^T: 4 key-fragments x 2 k-steps
    float sv[4][4];
#pragma unroll
    for (int kb4 = 0; kb4 < 4; ++kb4) {
      f32x4 S = {0.f, 0.f, 0.f, 0.f};
      bf16x8 B0 = *(const bf16x8*)&Klds[(kb4 << 4) + l15][(hi << 3)];
      bf16x8 B1 = *(const bf16x8*)&Klds[(kb4 << 4) + l15][32 + (hi << 3)];
      S = __builtin_amdgcn_mfma_f32_16x16x32_bf16(aQ0, B0, S, 0, 0, 0);
      S = __builtin_amdgcn_mfma_f32_16x16x32_bf16(aQ1, B1, S, 0, 0, 0);
      int key = (kt << 6) + (kb4 << 4) + l15;
#pragma unroll
      for (int r = 0; r < 4; ++r) {
        int qg = qrow0 + (hi << 2) + r;
        float val = S[r] * 0.125f;
        sv[kb4][r] = (key <= qg && key > qg - Wn) ? val : -INFINITY;
      }
    }

    // online softmax (row r lives in reg r; cols spread over 16 lanes of the hi-group)
    float scl[4], pv[4][4];
#pragma unroll
    for (int r = 0; r < 4; ++r) {
      float mt = fmaxf(fmaxf(sv[0][r], sv[1][r]), fmaxf(sv[2][r], sv[3][r]));
      mt = fmaxf(mt, __shfl_xor(mt, 1, 64));
      mt = fmaxf(mt, __shfl_xor(mt, 2, 64));
      mt = fmaxf(mt, __shfl_xor(mt, 4, 64));
      mt = fmaxf(mt, __shfl_xor(mt, 8, 64));
      float mn = fmaxf(mrow[r], mt);
      float sc = (mrow[r] > -INFINITY) ? __expf(mrow[r] - mn) : 0.f;
      float rs = 0.f;
#pragma unroll
      for (int kb4 = 0; kb4 < 4; ++kb4) {
        float p = (sv[kb4][r] > -INFINITY) ? __expf(sv[kb4][r] - mn) : 0.f;
        pv[kb4][r] = p;
        rs += p;
      }
      rs += __shfl_xor(rs, 1, 64);
      rs += __shfl_xor(rs, 2, 64);
      rs += __shfl_xor(rs, 4, 64);
      rs += __shfl_xor(rs, 8, 64);
      mrow[r] = mn;
      lrow[r] = lrow[r] * sc + rs;
      scl[r] = sc;
    }

    // write P (bf16) to wave-local LDS, rescale O
#pragma unroll
    for (int kb4 = 0; kb4 < 4; ++kb4)
#pragma unroll
      for (int r = 0; r < 4; ++r)
        Plds[wave][(hi << 2) + r][(kb4 << 4) + l15] = f2b(pv[kb4][r]);
#pragma unroll
    for (int df = 0; df < 4; ++df) {
      f32x4 t4 = o[df];
      t4[0] *= scl[0]; t4[1] *= scl[1]; t4[2] *= scl[2]; t4[3] *= scl[3];
      o[df] = t4;
    }

    // PV: A = P fragment (wave-local, compiler inserts lgkmcnt), B = Vt fragment
#pragma unroll
    for (int ks = 0; ks < 2; ++ks) {
      bf16x8 A = *(const bf16x8*)&Plds[wave][l15][(ks << 5) + (hi << 3)];
#pragma unroll
      for (int df = 0; df < 4; ++df) {
        bf16x8 Bv = *(const bf16x8*)&Vt[(df << 4) + l15][(ks << 5) + (hi << 3)];
        o[df] = __builtin_amdgcn_mfma_f32_16x16x32_bf16(A, Bv, o[df], 0, 0, 0);
      }
    }
  }

  float inv[4];
#pragma unroll
  for (int r = 0; r < 4; ++r) inv[r] = lrow[r] > 0.f ? 1.f / lrow[r] : 0.f;
#pragma unroll
  for (int r = 0; r < 4; ++r) {
    float* yp = y + ((size_t)((b << 11) + qrow0 + (hi << 2) + r) << 10) + (h << 6) + l15;
#pragma unroll
    for (int df = 0; df < 4; ++df) yp[df << 4] = o[df][r] * inv[r];
  }
}

// ---------------- router: sigmoid logits, top-2, counts ----------------
__global__ __launch_bounds__(256) void router_k(const float* __restrict__ h2,
                                                const float* __restrict__ rW,
                                                const float* __restrict__ bias,
                                                int* __restrict__ topi,
                                                float* __restrict__ topw,
                                                int* __restrict__ counts) {
  const int n = blockIdx.x;
  const int t = threadIdx.x;
  const int e = t >> 5, lane = t & 31;
  const float* hr = h2 + (size_t)n * CC;
  const float* wr = rW + (e << 10);
  float acc = 0.f;
  for (int j = lane; j < CC; j += 32) acc += hr[j] * wr[j];
#pragma unroll
  for (int off = 16; off; off >>= 1) acc += __shfl_xor(acc, off, 64);
  __shared__ float sc[8], sel[8];
  if (lane == 0) {
    float sg = 1.f / (1.f + __expf(-acc));
    sc[e] = sg;
    sel[e] = sg + bias[e];
  }
  __syncthreads();
  if (t == 0) {
    int i1 = 0; float b1 = sel[0];
    for (int j = 1; j < 8; ++j) if (sel[j] > b1) { b1 = sel[j]; i1 = j; }
    int i2 = -1; float b2 = -INFINITY;
    for (int j = 0; j < 8; ++j) if (j != i1 && sel[j] > b2) { b2 = sel[j]; i2 = j; }
    float w1 = sc[i1], w2 = sc[i2];
    float invs = 1.f / (w1 + w2 + 1e-20f);
    topi[n * 2] = i1; topi[n * 2 + 1] = i2;
    topw[n * 2] = w1 * invs; topw[n * 2 + 1] = w2 * invs;
    atomicAdd(&counts[i1], 1);
    atomicAdd(&counts[i2], 1);
  }
}

__global__ void scan_k(const int* __restrict__ counts, int* __restrict__ offsets) {
  if (threadIdx.x == 0 && blockIdx.x == 0) {
    int s = 0;
    for (int e = 0; e < 8; ++e) { offsets[e] = s; s += counts[e]; }
    offsets[8] = s;
  }
}

__global__ __launch_bounds__(256) void scatter_k(const int* __restrict__ topi,
                                                 const float* __restrict__ topw,
                                                 const int* __restrict__ offsets,
                                                 int* __restrict__ counts2,
                                                 int* __restrict__ tok_idx,
                                                 float* __restrict__ tok_w,
                                                 int* __restrict__ pospair) {
  int n = blockIdx.x * 256 + threadIdx.x;
  if (n >= NTOK) return;
  for (int kk = 0; kk < 2; ++kk) {
    int e = topi[n * 2 + kk];
    int slot = atomicAdd(&counts2[e], 1);
    int p = offsets[e] + slot;
    tok_idx[p] = n;
    tok_w[p] = topw[n * 2 + kk];
    pospair[n * 2 + kk] = p;
  }
}

// ---------------- expert fc: he[pair,i] = relu(h2[tok] @ Wfc[e]^T)^2 (gathered) ----------------
__global__ __launch_bounds__(256) void exp_fc_k(const float* __restrict__ h2,
                                                const float* __restrict__ Wfc,
                                                const int* __restrict__ offsets,
                                                const int* __restrict__ counts,
                                                const int* __restrict__ tok_idx,
                                                float* __restrict__ he) {
  const int e = blockIdx.z;
  const int cnt = counts[e];
  const int mt = blockIdx.y << 6;
  if (mt >= cnt) return;
  const int base = offsets[e];
  __shared__ float As[16][68];
  __shared__ float Ws[16][68];
  const int t = threadIdx.x;
  const int bn = blockIdx.x << 6;
  const int lrow = t >> 2, lk = (t & 3) << 2;
  const int tm = (t >> 4) << 2, tn = (t & 15) << 2;
  int r = mt + lrow;
  int token = tok_idx[base + (r < cnt ? r : cnt - 1)];
  const float* Ap = h2 + (size_t)token * CC + lk;
  const float* Wp = Wfc + ((size_t)e << 20) + (size_t)(bn + lrow) * CC + lk;
  float acc[4][4] = {};
  for (int k0 = 0; k0 < CC; k0 += 16) {
    float4 a4 = *(const float4*)(Ap + k0);
    float4 w4 = *(const float4*)(Wp + k0);
    __syncthreads();
    As[lk + 0][lrow] = a4.x; As[lk + 1][lrow] = a4.y;
    As[lk + 2][lrow] = a4.z; As[lk + 3][lrow] = a4.w;
    Ws[lk + 0][lrow] = w4.x; Ws[lk + 1][lrow] = w4.y;
    Ws[lk + 2][lrow] = w4.z; Ws[lk + 3][lrow] = w4.w;
    __syncthreads();
#pragma unroll
    for (int kk = 0; kk < 16; ++kk) {
      float4 av = *(const float4*)&As[kk][tm];
      float4 wv = *(const float4*)&Ws[kk][tn];
      float am[4] = {av.x, av.y, av.z, av.w};
      float wn[4] = {wv.x, wv.y, wv.z, wv.w};
#pragma unroll
      for (int i = 0; i < 4; ++i)
#pragma unroll
        for (int j = 0; j < 4; ++j) acc[i][j] += am[i] * wn[j];
    }
  }
#pragma unroll
  for (int i = 0; i < 4; ++i) {
    int rr = mt + tm + i;
    if (rr < cnt) {
      size_t off = (size_t)(base + rr) * II + bn + tn;
      float4 vv;
      vv.x = acc[i][0] > 0.f ? acc[i][0] * acc[i][0] : 0.f;
      vv.y = acc[i][1] > 0.f ? acc[i][1] * acc[i][1] : 0.f;
      vv.z = acc[i][2] > 0.f ? acc[i][2] * acc[i][2] : 0.f;
      vv.w = acc[i][3] > 0.f ? acc[i][3] * acc[i][3] : 0.f;
      *(float4*)(he + off) = vv;
    }
  }
}

// ---------------- expert proj: pairout[pair,c] = w * (he[pair] @ Wproj[e]^T) ----------------
__global__ __launch_bounds__(256) void exp_proj_k(const float* __restrict__ he,
                                                  const float* __restrict__ Wproj,
                                                  const int* __restrict__ offsets,
                                                  const int* __restrict__ counts,
                                                  const float* __restrict__ tok_w,
                                                  float* __restrict__ pairout) {
  const int e = blockIdx.z;
  const int cnt = counts[e];
  const int mt = blockIdx.y << 6;
  if (mt >= cnt) return;
  const int base = offsets[e];
  __shared__ float As[16][68];
  __shared__ float Ws[16][68];
  const int t = threadIdx.x;
  const int bn = blockIdx.x << 6;
  const int lrow = t >> 2, lk = (t & 3) << 2;
  const int tm = (t >> 4) << 2, tn = (t & 15) << 2;
  int r = mt + lrow;
  int ridx = base + (r < cnt ? r : cnt - 1);
  const float* Ap = he + (size_t)ridx * II + lk;
  const float* Wp = Wproj + ((size_t)e << 20) + (size_t)(bn + lrow) * II + lk;
  float acc[4][4] = {};
  for (int k0 = 0; k0 < II; k0 += 16) {
    float4 a4 = *(const float4*)(Ap + k0);
    float4 w4 = *(const float4*)(Wp + k0);
    __syncthreads();
    As[lk + 0][lrow] = a4.x; As[lk + 1][lrow] = a4.y;
    As[lk + 2][lrow] = a4.z; As[lk + 3][lrow] = a4.w;
    Ws[lk + 0][lrow] = w4.x; Ws[lk + 1][lrow] = w4.y;
    Ws[lk + 2][lrow] = w4.z; Ws[lk + 3][lrow] = w4.w;
    __syncthreads();
#pragma unroll
    for (int kk = 0; kk < 16; ++kk) {
      float4 av = *(const float4*)&As[kk][tm];
      float4 wv = *(const float4*)&Ws[kk][tn];
      float am[4] = {av.x, av.y, av.z, av.w};
      float wn[4] = {wv.x, wv.y, wv.z, wv.w};
#pragma unroll
      for (int i = 0; i < 4; ++i)
#pragma unroll
        for (int j = 0; j < 4; ++j) acc[i][j] += am[i] * wn[j];
    }
  }
#pragma unroll
  for (int i = 0; i < 4; ++i) {
    int rr = mt + tm + i;
    if (rr < cnt) {
      float wgt = tok_w[base + rr];
      size_t off = (size_t)(base + rr) * CC + bn + tn;
      float4 vv = make_float4(acc[i][0] * wgt, acc[i][1] * wgt, acc[i][2] * wgt, acc[i][3] * wgt);
      *(float4*)(pairout + off) = vv;
    }
  }
}

// ---------------- final: out[n] += pairout[p0] + pairout[p1] ----------------
__global__ __launch_bounds__(256) void final_add_k(float* __restrict__ out,
                                                   const float* __restrict__ pairout,
                                                   const int* __restrict__ pospair) {
  int n = blockIdx.x, t = threadIdx.x;
  int p0 = pospair[n * 2], p1 = pospair[n * 2 + 1];
  float4* o = (float4*)(out + (size_t)n * CC);
  const float4* a = (const float4*)(pairout + (size_t)p0 * CC);
  const float4* b4 = (const float4*)(pairout + (size_t)p1 * CC);
  float4 vo = o[t], va = a[t], vb = b4[t];
  vo.x += va.x + vb.x; vo.y += va.y + vb.y;
  vo.z += va.z + vb.z; vo.w += va.w + vb.w;
  o[t] = vo;
}

extern "C" void kernel_launch(void* const* d_in, const int* in_sizes, int n_in,
                              void* d_out, int out_size, void* d_ws, size_t ws_size,
                              hipStream_t stream) {
  const float* x = (const float*)d_in[0];
  const float* ve = (const float*)d_in[1];
  const float* cosb = (const float*)d_in[2];
  const float* sinb = (const float*)d_in[3];
  const float* Wq = (const float*)d_in[4];
  const float* Wk = (const float*)d_in[5];
  const float* Wv = (const float*)d_in[6];
  const float* Wo = (const float*)d_in[7];
  const float* gW = (const float*)d_in[8];
  const float* routerW = (const float*)d_in[9];
  const float* bias = (const float*)d_in[10];
  const float* Wsfc = (const float*)d_in[11];
  const float* Wsproj = (const float*)d_in[12];
  const float* Wefc = (const float*)d_in[13];
  const float* Weproj = (const float*)d_in[14];
  const int* wsz = (const int*)d_in[15];
  float* out = (float*)d_out;
  float* wsf = (float*)d_ws;

  // workspace layout (floats); same footprint as R0 (~88.2 MB)
  float* h = wsf;                       // 0 .. 4,194,304
  float* q = wsf + 4194304;             // fp32 q (pre-rope)
  float* kbuf = wsf + 8388608;          // fp32 k (pre-rope)
  float* vbuf = wsf + 9437184;          // fp32 v (pre-gate)
  float* y = wsf + 10485760;            // attention out fp32
  float* he = wsf + 4194304;            // aliases q/kbuf/vbuf/y-prefix (dead in expert phase)
  float* x2 = wsf + 14680064;
  float* h2 = wsf + 18874368;
  float* s1 = h;                        // alias (h dead after gate_k)
  float* pairout = wsf + 14680064;      // aliases x2+h2 (dead by expert phase)
  // bf16 buffers aliased into dead fp32 regions:
  u16* qb = (u16*)(wsf);                // in h region; written by rope_rms (h dead), dead before s1
  u16* kb16 = (u16*)(wsf + 2097152);    // in h region
  u16* vb = (u16*)(wsf + 14680064);     // in x2 region; dead before x2 written
  int* meta = (int*)(wsf + 23068672);
  int* counts = meta;
  int* counts2 = meta + 8;
  int* offsets = meta + 16;
  int* topi = meta + 32;
  float* topw = (float*)(meta + 8224);
  int* tok_idx = meta + 16416;
  float* tok_w = (float*)(meta + 24608);
  int* pospair = meta + 32800;

  hipMemsetAsync(counts, 0, 16 * sizeof(int), stream);

  rmsnorm_k<<<NTOK, 256, 0, stream>>>(x, h);
  gemm_k<EPI_NONE><<<dim3(16, 64), 256, 0, stream>>>(h, Wq, q, nullptr, 1024, 1024);
  gemm_k<EPI_NONE><<<dim3(4, 64), 256, 0, stream>>>(h, Wk, kbuf, nullptr, 256, 1024);
  gemm_k<EPI_NONE><<<dim3(4, 64), 256, 0, stream>>>(h, Wv, vbuf, nullptr, 256, 1024);
  gate_k<<<NTOK, 256, 0, stream>>>(h, ve, gW, vbuf, vb);           // h now dead
  rope_rms_k<<<NTOK, 256, 0, stream>>>(q, kbuf, cosb, sinb, qb, kb16);
  attn_mfma_k<<<dim3(TT / 64, HH, BB), 256, 0, stream>>>(qb, kb16, vb, y, wsz);
  gemm_k<EPI_ADD><<<dim3(16, 64), 256, 0, stream>>>(y, Wo, x2, x, 1024, 1024);
  rmsnorm_k<<<NTOK, 256, 0, stream>>>(x2, h2);
  gemm_k<EPI_RELUSQ><<<dim3(16, 64), 256, 0, stream>>>(h2, Wsfc, s1, nullptr, 1024, 1024);
  gemm_k<EPI_ADD><<<dim3(16, 64), 256, 0, stream>>>(s1, Wsproj, out, x2, 1024, 1024);
  router_k<<<NTOK, 256, 0, stream>>>(h2, routerW, bias, topi, topw, counts);
  scan_k<<<1, 64, 0, stream>>>(counts, offsets);
  scatter_k<<<16, 256, 0, stream>>>(topi, topw, offsets, counts2, tok_idx, tok_w, pospair);
  exp_fc_k<<<dim3(16, 64, 8), 256, 0, stream>>>(h2, Wefc, offsets, counts, tok_idx, he);
  exp_proj_k<<<dim3(16, 64, 8), 256, 0, stream>>>(he, Weproj, offsets, counts, tok_w, pairout);
  final_add_k<<<NTOK, 256, 0, stream>>>(out, pairout, pospair);
}

// Round 4
// 548.100 us; speedup vs baseline: 4.5268x; 2.4983x over previous
//
#include <hip/hip_runtime.h>

// Problem constants
#define TT 2048
#define CC 1024
#define NTOK 4096
#define EPSF 1.1920929e-07f

typedef unsigned short u16;
typedef short bf16x8 __attribute__((ext_vector_type(8)));
typedef u16 u16x4 __attribute__((ext_vector_type(4)));
typedef float f32x4 __attribute__((ext_vector_type(4)));

__device__ __forceinline__ u16 f2b(float f) {
  union { float f; unsigned u; } v; v.f = f;
  unsigned r = v.u + 0x7FFFu + ((v.u >> 16) & 1u);
  return (u16)(r >> 16);
}
__device__ __forceinline__ float b2f(u16 u) {
  union { unsigned u; float f; } v; v.u = ((unsigned)u) << 16;
  return v.f;
}
__device__ __forceinline__ void gload16(const u16* g, u16* l) {
  __builtin_amdgcn_global_load_lds(
      (const __attribute__((address_space(1))) void*)g,
      (__attribute__((address_space(3))) void*)l, 16, 0, 0);
}
// swizzled LDS fragment read: tile [128 rows][64 u16], phys seg = kseg ^ (row&7)
__device__ __forceinline__ bf16x8 ldsf(const u16* s, int row, int kseg) {
  return *(const bf16x8*)(s + (row << 6) + ((kseg ^ (row & 7)) << 3));
}

// ---------------- fp32 -> bf16 converts ----------------
__global__ __launch_bounds__(256) void cvt_bf16_k(const float* __restrict__ in,
                                                  u16* __restrict__ out) {
  int i = (blockIdx.x * 256 + threadIdx.x) * 8;
  float4 a = *(const float4*)(in + i);
  float4 b = *(const float4*)(in + i + 4);
  u16 r[8] = {f2b(a.x), f2b(a.y), f2b(a.z), f2b(a.w),
              f2b(b.x), f2b(b.y), f2b(b.z), f2b(b.w)};
  *(bf16x8*)(out + i) = *(bf16x8*)r;
}

__global__ __launch_bounds__(256) void cvt_split_k(const float* __restrict__ in,
                                                   u16* __restrict__ hi,
                                                   u16* __restrict__ lo) {
  int i = (blockIdx.x * 256 + threadIdx.x) * 8;
  float v[8];
  *(float4*)v = *(const float4*)(in + i);
  *(float4*)(v + 4) = *(const float4*)(in + i + 4);
  u16 h[8], l[8];
#pragma unroll
  for (int j = 0; j < 8; ++j) {
    h[j] = f2b(v[j]);
    l[j] = f2b(v[j] - b2f(h[j]));
  }
  *(bf16x8*)(hi + i) = *(bf16x8*)h;
  *(bf16x8*)(lo + i) = *(bf16x8*)l;
}

// ---------------- RMSNorm -> split bf16 (hi/lo) ----------------
__global__ __launch_bounds__(256) void rmsnorm_split_k(const float* __restrict__ in,
                                                       u16* __restrict__ hio,
                                                       u16* __restrict__ loo) {
  const int rowi = blockIdx.x;
  const int t = threadIdx.x;
  float4 v = ((const float4*)(in + (size_t)rowi * CC))[t];
  float ss = v.x * v.x + v.y * v.y + v.z * v.z + v.w * v.w;
#pragma unroll
  for (int off = 32; off; off >>= 1) ss += __shfl_down(ss, off, 64);
  __shared__ float red[4];
  if ((t & 63) == 0) red[t >> 6] = ss;
  __syncthreads();
  float tot = red[0] + red[1] + red[2] + red[3];
  float sc = rsqrtf(tot * (1.0f / CC) + EPSF);
  float o[4] = {v.x * sc, v.y * sc, v.z * sc, v.w * sc};
  u16 h[4], l[4];
#pragma unroll
  for (int j = 0; j < 4; ++j) {
    h[j] = f2b(o[j]);
    l[j] = f2b(o[j] - b2f(h[j]));
  }
  *(u16x4*)(hio + (size_t)rowi * CC + t * 4) = *(u16x4*)h;
  *(u16x4*)(loo + (size_t)rowi * CC + t * 4) = *(u16x4*)l;
}

// ---------------- RMSNorm(x2) -> bf16 h2 + fp32 router logits ----------------
__global__ __launch_bounds__(256) void rmsnorm_logits_k(const float* __restrict__ in,
                                                        u16* __restrict__ b16o,
                                                        const float* __restrict__ rW,
                                                        float* __restrict__ logits) {
  const int rowi = blockIdx.x;
  const int t = threadIdx.x;
  float4 v = ((const float4*)(in + (size_t)rowi * CC))[t];
  float ss = v.x * v.x + v.y * v.y + v.z * v.z + v.w * v.w;
#pragma unroll
  for (int off = 32; off; off >>= 1) ss += __shfl_down(ss, off, 64);
  __shared__ float red[4];
  __shared__ float red2[8][4];
  if ((t & 63) == 0) red[t >> 6] = ss;
  __syncthreads();
  float tot = red[0] + red[1] + red[2] + red[3];
  float sc = rsqrtf(tot * (1.0f / CC) + EPSF);
  float o[4] = {v.x * sc, v.y * sc, v.z * sc, v.w * sc};
  u16 h[4] = {f2b(o[0]), f2b(o[1]), f2b(o[2]), f2b(o[3])};
  *(u16x4*)(b16o + (size_t)rowi * CC + t * 4) = *(u16x4*)h;
  // router logits in fp32
  const float* rwp = rW + (t << 2);
  float part[8];
#pragma unroll
  for (int e = 0; e < 8; ++e) {
    const float* w = rwp + (e << 10);
    part[e] = o[0] * w[0] + o[1] * w[1] + o[2] * w[2] + o[3] * w[3];
  }
  const int wid = t >> 6;
#pragma unroll
  for (int e = 0; e < 8; ++e) {
    float p = part[e];
#pragma unroll
    for (int off = 32; off; off >>= 1) p += __shfl_down(p, off, 64);
    if ((t & 63) == 0) red2[e][wid] = p;
  }
  __syncthreads();
  if (t < 8) logits[rowi * 8 + t] = red2[t][0] + red2[t][1] + red2[t][2] + red2[t][3];
}

// ---------------- gates[n][kh] = 2*sigmoid(h[n,:32] @ gW[kh]) ----------------
__global__ __launch_bounds__(256) void gates_k(const u16* __restrict__ hb,
                                               const float* __restrict__ gW,
                                               float* __restrict__ gates) {
  int idx = blockIdx.x * 256 + threadIdx.x;  // token*4 + kh
  int tok = idx >> 2, kh = idx & 3;
  const u16* hr = hb + (size_t)tok * CC;
  const float* gw = gW + (kh << 5);
  float dot = 0.f;
#pragma unroll
  for (int j = 0; j < 32; ++j) dot += b2f(hr[j]) * gw[j];
  gates[idx] = 2.f / (1.f + __expf(-dot));
}

// ---------------- bf16 MFMA GEMM: C[M,N] = A[M,K] @ W[N,K]^T ----------------
// 128x128 tile, BK=64, 4 waves (2x2). MODE:
// 1 plain, f32 out += addv        (shared proj -> out)
// 3 plain, relu^2 bf16 out        (shared fc)
// 4 plain, gathered A, relu^2 bf16 (expert fc)
// 5 plain, gathered rows, w*atomicAdd f32 (expert proj)
// 6 split(3-mfma), f32 out += addv (Wo -> x2)
// 9 split, rope+head-rms epilogue, bf16 out (q,k)
// 10 split, ve-gate epilogue, bf16 out (v)
template <int MODE>
__global__ __launch_bounds__(256) void gemm_bf_k(
    const u16* __restrict__ A, const u16* __restrict__ A2,
    const u16* __restrict__ Wt, const u16* __restrict__ W2,
    float* __restrict__ Cf, u16* __restrict__ Cb,
    const float* __restrict__ addv, int N, int K,
    const int* __restrict__ offsets, const int* __restrict__ counts,
    const int* __restrict__ tok_idx, const float* __restrict__ tok_w,
    const float* __restrict__ cosb, const float* __restrict__ sinb,
    const float* __restrict__ gates, const float* __restrict__ vein) {
  constexpr bool SPLIT = (MODE == 6 || MODE == 9 || MODE == 10);
  constexpr int NS = SPLIT ? 2 : 1;
  __shared__ __align__(16) u16 Asw[NS * 8192];
  __shared__ __align__(16) u16 Bsw[NS * 8192];
  const int t = threadIdx.x;
  const int lane = t & 63;
  const int l15 = lane & 15, hi = lane >> 4;
  const int wave = t >> 6;
  const int wr = wave >> 1, wc = wave & 1;
  const int e = blockIdx.z;
  const int mt = blockIdx.y << 7;
  const int bn = blockIdx.x << 7;
  int base = 0, cnt = 0;
  if (MODE == 4 || MODE == 5) {
    cnt = counts[e];
    if (mt >= cnt) return;
    base = offsets[e];
  }
  const int r8 = t >> 3;
  const int ksg = (t & 7) ^ (r8 & 7);  // inverse-swizzled global k-segment
  const u16* asrc[4];
  const u16* bsrc[4];
  const u16* asrc2[4];
  const u16* bsrc2[4];
  const u16* Wb = Wt + ((MODE == 4 || MODE == 5) ? ((size_t)e << 20) : (size_t)0);
#pragma unroll
  for (int g = 0; g < 4; ++g) {
    int rl = (g << 5) + r8;
    int arow;
    if (MODE == 4) {
      int rr = mt + rl; if (rr > cnt - 1) rr = cnt - 1;
      arow = tok_idx[base + rr];
    } else if (MODE == 5) {
      int rr = mt + rl; if (rr > cnt - 1) rr = cnt - 1;
      arow = base + rr;
    } else {
      arow = mt + rl;
    }
    size_t ao = (size_t)arow * K + (ksg << 3);
    size_t bo = (size_t)(bn + rl) * K + (ksg << 3);
    asrc[g] = A + ao;
    bsrc[g] = Wb + bo;
    if (SPLIT) { asrc2[g] = A2 + ao; bsrc2[g] = W2 + bo; }
  }
  f32x4 acc[4][4] = {};
  const int nkt = K >> 6;
  for (int kt = 0; kt < nkt; ++kt) {
    __syncthreads();
    const int ko = kt << 6;
#pragma unroll
    for (int g = 0; g < 4; ++g) {
      int co = ((g << 8) + t) << 3;
      gload16(asrc[g] + ko, &Asw[co]);
      gload16(bsrc[g] + ko, &Bsw[co]);
      if (SPLIT) {
        gload16(asrc2[g] + ko, &Asw[8192 + co]);
        gload16(bsrc2[g] + ko, &Bsw[8192 + co]);
      }
    }
    __syncthreads();
#pragma unroll
    for (int kk = 0; kk < 2; ++kk) {
      bf16x8 ah[4], bh[4];
#pragma unroll
      for (int mi = 0; mi < 4; ++mi)
        ah[mi] = ldsf(Asw, (wr << 6) + (mi << 4) + l15, (kk << 2) + hi);
#pragma unroll
      for (int nj = 0; nj < 4; ++nj)
        bh[nj] = ldsf(Bsw, (wc << 6) + (nj << 4) + l15, (kk << 2) + hi);
#pragma unroll
      for (int mi = 0; mi < 4; ++mi)
#pragma unroll
        for (int nj = 0; nj < 4; ++nj)
          acc[mi][nj] = __builtin_amdgcn_mfma_f32_16x16x32_bf16(ah[mi], bh[nj], acc[mi][nj], 0, 0, 0);
      if (SPLIT) {
        bf16x8 al[4], bl[4];
#pragma unroll
        for (int mi = 0; mi < 4; ++mi)
          al[mi] = ldsf(Asw + 8192, (wr << 6) + (mi << 4) + l15, (kk << 2) + hi);
#pragma unroll
        for (int nj = 0; nj < 4; ++nj)
          bl[nj] = ldsf(Bsw + 8192, (wc << 6) + (nj << 4) + l15, (kk << 2) + hi);
#pragma unroll
        for (int mi = 0; mi < 4; ++mi)
#pragma unroll
          for (int nj = 0; nj < 4; ++nj)
            acc[mi][nj] = __builtin_amdgcn_mfma_f32_16x16x32_bf16(ah[mi], bl[nj], acc[mi][nj], 0, 0, 0);
#pragma unroll
        for (int mi = 0; mi < 4; ++mi)
#pragma unroll
          for (int nj = 0; nj < 4; ++nj)
            acc[mi][nj] = __builtin_amdgcn_mfma_f32_16x16x32_bf16(al[mi], bh[nj], acc[mi][nj], 0, 0, 0);
      }
    }
  }
  // ---- epilogues (C/D layout: col=l15, row=hi*4+r) ----
  if (MODE == 9) {
    // rope + per-head rmsnorm; wave's col block = one head (64 dims)
#pragma unroll
    for (int mi = 0; mi < 4; ++mi) {
#pragma unroll
      for (int r = 0; r < 4; ++r) {
        int row = mt + (wr << 6) + (mi << 4) + (hi << 2) + r;
        int tpos = row & (TT - 1);
        const float* cp = cosb + (tpos << 5);
        const float* sp = sinb + (tpos << 5);
        float c0 = cp[l15], s0 = sp[l15];
        float c1 = cp[16 + l15], s1 = sp[16 + l15];
        float a0 = acc[mi][0][r], a1 = acc[mi][1][r];
        float b0 = acc[mi][2][r], b1 = acc[mi][3][r];
        float r00 = a0 * c0 + b0 * s0;
        float r01 = a1 * c1 + b1 * s1;
        float r10 = b0 * c0 - a0 * s0;
        float r11 = b1 * c1 - a1 * s1;
        float ss = r00 * r00 + r01 * r01 + r10 * r10 + r11 * r11;
        ss += __shfl_xor(ss, 1, 64); ss += __shfl_xor(ss, 2, 64);
        ss += __shfl_xor(ss, 4, 64); ss += __shfl_xor(ss, 8, 64);
        float scn = rsqrtf(ss * (1.f / 64.f) + EPSF);
        u16* qp = Cb + (size_t)row * N + bn + (wc << 6);
        qp[l15]      = f2b(r00 * scn);
        qp[16 + l15] = f2b(r01 * scn);
        qp[32 + l15] = f2b(r10 * scn);
        qp[48 + l15] = f2b(r11 * scn);
      }
    }
    return;
  }
  if (MODE == 10) {
    int kvh = (bn + (wc << 6)) >> 6;
#pragma unroll
    for (int mi = 0; mi < 4; ++mi) {
#pragma unroll
      for (int r = 0; r < 4; ++r) {
        int row = mt + (wr << 6) + (mi << 4) + (hi << 2) + r;
        float g = gates[(row << 2) + kvh];
        const float* vep = vein + ((size_t)row << 8) + (kvh << 6);
        u16* vp = Cb + (size_t)row * N + bn + (wc << 6);
#pragma unroll
        for (int nj = 0; nj < 4; ++nj) {
          int d = (nj << 4) + l15;
          vp[d] = f2b(acc[mi][nj][r] + g * vep[d]);
        }
      }
    }
    return;
  }
#pragma unroll
  for (int mi = 0; mi < 4; ++mi) {
#pragma unroll
    for (int r = 0; r < 4; ++r) {
      int rl = (wr << 6) + (mi << 4) + (hi << 2) + r;
      if (MODE == 4 || MODE == 5) {
        int rr = mt + rl;
        if (rr >= cnt) continue;
        if (MODE == 4) {
          size_t ro = (size_t)(base + rr) * N;
#pragma unroll
          for (int nj = 0; nj < 4; ++nj) {
            float v = acc[mi][nj][r];
            v = v > 0.f ? v * v : 0.f;
            Cb[ro + bn + (wc << 6) + (nj << 4) + l15] = f2b(v);
          }
        } else {
          int tok = tok_idx[base + rr];
          float w = tok_w[base + rr];
          size_t ro = (size_t)tok * N;
#pragma unroll
          for (int nj = 0; nj < 4; ++nj)
            atomicAdd(&Cf[ro + bn + (wc << 6) + (nj << 4) + l15], acc[mi][nj][r] * w);
        }
      } else {
        size_t ro = (size_t)(mt + rl) * N;
#pragma unroll
        for (int nj = 0; nj < 4; ++nj) {
          int col = bn + (wc << 6) + (nj << 4) + l15;
          float v = acc[mi][nj][r];
          if (MODE == 1 || MODE == 6) {
            Cf[ro + col] = v + addv[ro + col];
          } else {  // MODE 3
            v = v > 0.f ? v * v : 0.f;
            Cb[ro + col] = f2b(v);
          }
        }
      }
    }
  }
}

// ---------------- flash attention, bf16 MFMA, 64x64 tiles, split-y out ----------------
__global__ __launch_bounds__(256) void attn_mfma_k(const u16* __restrict__ qb,
                                                   const u16* __restrict__ kb,
                                                   const u16* __restrict__ vb,
                                                   u16* __restrict__ yh,
                                                   u16* __restrict__ yl,
                                                   const int* __restrict__ wszp) {
  const int b = blockIdx.z, h = blockIdx.y, qt = blockIdx.x;
  const int kvh = h >> 2;
  const int Wn = *wszp;
  const int t = threadIdx.x;
  const int lane = t & 63, wave = t >> 6;
  const int l15 = lane & 15, hi = lane >> 4;

  __shared__ u16 Klds[64][72];
  __shared__ u16 Vt[64][72];
  __shared__ u16 Plds[4][16][72];

  const int qrow0 = (qt << 6) + (wave << 4);
  bf16x8 aQ0, aQ1;
  {
    const u16* qp = qb + ((size_t)((b << 11) + qrow0 + l15) << 10) + (h << 6) + (hi << 3);
    aQ0 = *(const bf16x8*)qp;
    aQ1 = *(const bf16x8*)(qp + 32);
  }
  f32x4 o[4] = {};
  float mrow[4] = {-INFINITY, -INFINITY, -INFINITY, -INFINITY};
  float lrow[4] = {0.f, 0.f, 0.f, 0.f};
  int lo = (qt << 6) - Wn + 1;
  int kt0 = lo > 0 ? (lo >> 6) : 0;

  for (int kt = kt0; kt <= qt; ++kt) {
    __syncthreads();
#pragma unroll
    for (int i = 0; i < 2; ++i) {
      int lin = t + (i << 8);
      int r = lin >> 3, c = lin & 7;
      const u16* kp = kb + ((size_t)((b << 11) + (kt << 6) + r) << 8) + (kvh << 6) + (c << 3);
      *(bf16x8*)&Klds[r][c << 3] = *(const bf16x8*)kp;
    }
#pragma unroll
    for (int i = 0; i < 2; ++i) {
      int key = t & 63;
      int d0 = ((t >> 6) << 3) + (i << 5);
      const u16* vp = vb + ((size_t)((b << 11) + (kt << 6) + key) << 8) + (kvh << 6) + d0;
      bf16x8 vv = *(const bf16x8*)vp;
#pragma unroll
      for (int j = 0; j < 8; ++j) Vt[d0 + j][key] = (u16)vv[j];
    }
    __syncthreads();

    float sv[4][4];
#pragma unroll
    for (int kb4 = 0; kb4 < 4; ++kb4) {
      f32x4 S = {0.f, 0.f, 0.f, 0.f};
      bf16x8 B0 = *(const bf16x8*)&Klds[(kb4 << 4) + l15][(hi << 3)];
      bf16x8 B1 = *(const bf16x8*)&Klds[(kb4 << 4) + l15][32 + (hi << 3)];
      S = __builtin_amdgcn_mfma_f32_16x16x32_bf16(aQ0, B0, S, 0, 0, 0);
      S = __builtin_amdgcn_mfma_f32_16x16x32_bf16(aQ1, B1, S, 0, 0, 0);
      int key = (kt << 6) + (kb4 << 4) + l15;
#pragma unroll
      for (int r = 0; r < 4; ++r) {
        int qg = qrow0 + (hi << 2) + r;
        float val = S[r] * 0.125f;
        sv[kb4][r] = (key <= qg && key > qg - Wn) ? val : -INFINITY;
      }
    }

    float scl[4], pv[4][4];
#pragma unroll
    for (int r = 0; r < 4; ++r) {
      float mt = fmaxf(fmaxf(sv[0][r], sv[1][r]), fmaxf(sv[2][r], sv[3][r]));
      mt = fmaxf(mt, __shfl_xor(mt, 1, 64));
      mt = fmaxf(mt, __shfl_xor(mt, 2, 64));
      mt = fmaxf(mt, __shfl_xor(mt, 4, 64));
      mt = fmaxf(mt, __shfl_xor(mt, 8, 64));
      float mn = fmaxf(mrow[r], mt);
      float sc = (mrow[r] > -INFINITY) ? __expf(mrow[r] - mn) : 0.f;
      float rs = 0.f;
#pragma unroll
      for (int kb4 = 0; kb4 < 4; ++kb4) {
        float p = (sv[kb4][r] > -INFINITY) ? __expf(sv[kb4][r] - mn) : 0.f;
        pv[kb4][r] = p;
        rs += p;
      }
      rs += __shfl_xor(rs, 1, 64);
      rs += __shfl_xor(rs, 2, 64);
      rs += __shfl_xor(rs, 4, 64);
      rs += __shfl_xor(rs, 8, 64);
      mrow[r] = mn;
      lrow[r] = lrow[r] * sc + rs;
      scl[r] = sc;
    }

#pragma unroll
    for (int kb4 = 0; kb4 < 4; ++kb4)
#pragma unroll
      for (int r = 0; r < 4; ++r)
        Plds[wave][(hi << 2) + r][(kb4 << 4) + l15] = f2b(pv[kb4][r]);
#pragma unroll
    for (int df = 0; df < 4; ++df) {
      f32x4 t4 = o[df];
      t4[0] *= scl[0]; t4[1] *= scl[1]; t4[2] *= scl[2]; t4[3] *= scl[3];
      o[df] = t4;
    }

#pragma unroll
    for (int ks = 0; ks < 2; ++ks) {
      bf16x8 Ap = *(const bf16x8*)&Plds[wave][l15][(ks << 5) + (hi << 3)];
#pragma unroll
      for (int df = 0; df < 4; ++df) {
        bf16x8 Bv = *(const bf16x8*)&Vt[(df << 4) + l15][(ks << 5) + (hi << 3)];
        o[df] = __builtin_amdgcn_mfma_f32_16x16x32_bf16(Ap, Bv, o[df], 0, 0, 0);
      }
    }
  }

  float inv[4];
#pragma unroll
  for (int r = 0; r < 4; ++r) inv[r] = lrow[r] > 0.f ? 1.f / lrow[r] : 0.f;
#pragma unroll
  for (int r = 0; r < 4; ++r) {
    size_t rbase = ((size_t)((b << 11) + qrow0 + (hi << 2) + r) << 10) + (h << 6) + l15;
#pragma unroll
    for (int df = 0; df < 4; ++df) {
      float f = o[df][r] * inv[r];
      u16 hv = f2b(f);
      yh[rbase + (df << 4)] = hv;
      yl[rbase + (df << 4)] = f2b(f - b2f(hv));
    }
  }
}

// ---------------- top-2 router from precomputed logits ----------------
__global__ __launch_bounds__(256) void topk_k(const float* __restrict__ logits,
                                              const float* __restrict__ bias,
                                              int* __restrict__ topi,
                                              float* __restrict__ topw,
                                              int* __restrict__ counts) {
  int n = blockIdx.x * 256 + threadIdx.x;
  if (n >= NTOK) return;
  float sc[8], sel[8];
#pragma unroll
  for (int e2 = 0; e2 < 8; ++e2) {
    float sg = 1.f / (1.f + __expf(-logits[n * 8 + e2]));
    sc[e2] = sg;
    sel[e2] = sg + bias[e2];
  }
  int i1 = 0; float b1 = sel[0];
#pragma unroll
  for (int j = 1; j < 8; ++j) if (sel[j] > b1) { b1 = sel[j]; i1 = j; }
  int i2 = -1; float b2 = -INFINITY;
#pragma unroll
  for (int j = 0; j < 8; ++j) if (j != i1 && sel[j] > b2) { b2 = sel[j]; i2 = j; }
  float w1 = sc[i1], w2 = sc[i2];
  float invs = 1.f / (w1 + w2 + 1e-20f);
  topi[n * 2] = i1; topi[n * 2 + 1] = i2;
  topw[n * 2] = w1 * invs; topw[n * 2 + 1] = w2 * invs;
  atomicAdd(&counts[i1], 1);
  atomicAdd(&counts[i2], 1);
}

__global__ void scan_k(const int* __restrict__ counts, int* __restrict__ offsets) {
  if (threadIdx.x == 0 && blockIdx.x == 0) {
    int s = 0;
    for (int e2 = 0; e2 < 8; ++e2) { offsets[e2] = s; s += counts[e2]; }
    offsets[8] = s;
  }
}

__global__ __launch_bounds__(256) void scatter_k(const int* __restrict__ topi,
                                                 const float* __restrict__ topw,
                                                 const int* __restrict__ offsets,
                                                 int* __restrict__ counts2,
                                                 int* __restrict__ tok_idx,
                                                 float* __restrict__ tok_w) {
  int n = blockIdx.x * 256 + threadIdx.x;
  if (n >= NTOK) return;
  for (int kk = 0; kk < 2; ++kk) {
    int e2 = topi[n * 2 + kk];
    int slot = atomicAdd(&counts2[e2], 1);
    int p = offsets[e2] + slot;
    tok_idx[p] = n;
    tok_w[p] = topw[n * 2 + kk];
  }
}

extern "C" void kernel_launch(void* const* d_in, const int* in_sizes, int n_in,
                              void* d_out, int out_size, void* d_ws, size_t ws_size,
                              hipStream_t stream) {
  const float* x = (const float*)d_in[0];
  const float* ve = (const float*)d_in[1];
  const float* cosb = (const float*)d_in[2];
  const float* sinb = (const float*)d_in[3];
  const float* Wq = (const float*)d_in[4];
  const float* Wk = (const float*)d_in[5];
  const float* Wv = (const float*)d_in[6];
  const float* Wo = (const float*)d_in[7];
  const float* gW = (const float*)d_in[8];
  const float* routerW = (const float*)d_in[9];
  const float* bias = (const float*)d_in[10];
  const float* Wsfc = (const float*)d_in[11];
  const float* Wsproj = (const float*)d_in[12];
  const float* Wefc = (const float*)d_in[13];
  const float* Weproj = (const float*)d_in[14];
  const int* wsz = (const int*)d_in[15];
  float* out = (float*)d_out;
  char* WS = (char*)d_ws;

  // ---- workspace layout (byte offsets), peak ~90.7 MiB ----
  u16* Wefc_b   = (u16*)(WS + 0);          // 16 MiB
  u16* Weproj_b = (u16*)(WS + 16777216);   // 16 MiB
  u16* Wsfc_b   = (u16*)(WS + 33554432);   // 2 MiB
  u16* Wsproj_b = (u16*)(WS + 35651584);   // 2 MiB
  u16* Wq_hi    = (u16*)(WS + 37748736);   // 2 MiB
  u16* Wq_lo    = (u16*)(WS + 39845888);   // 2 MiB
  u16* Wk_hi    = (u16*)(WS + 41943040);   // 0.5 MiB
  u16* Wk_lo    = (u16*)(WS + 42467328);   // 0.5 MiB
  u16* Wv_hi    = (u16*)(WS + 42991616);   // 0.5 MiB
  u16* Wv_lo    = (u16*)(WS + 43515904);   // 0.5 MiB
  u16* Wo_hi    = (u16*)(WS + 44040192);   // 2 MiB
  u16* Wo_lo    = (u16*)(WS + 46137344);   // 2 MiB
  u16* h_hi     = (u16*)(WS + 48234496);   // 8 MiB [dead after gates+QKV]
  u16* h_lo     = (u16*)(WS + 56623104);   // 8 MiB [dead after QKV]
  u16* qb       = (u16*)(WS + 65011712);   // 8 MiB [dead after attn]
  u16* kb       = (u16*)(WS + 73400320);   // 2 MiB [dead after attn]
  u16* vb       = (u16*)(WS + 75497472);   // 2 MiB [dead after attn]
  u16* y_hi     = (u16*)(WS + 77594624);   // 8 MiB [dead after Wo gemm]
  u16* y_lo     = (u16*)(WS + 85983232);   // 8 MiB [dead after Wo gemm]
  float* x2     = (float*)(WS + 48234496); // 16 MiB over h_hi+h_lo [written post-attn]
  u16* h2_b     = (u16*)(WS + 65011712);   // 8 MiB over qb [written post-Wo]
  u16* s1_b     = (u16*)(WS + 77594624);   // 8 MiB over y_hi [written post-Wo]
  u16* he_b     = (u16*)(WS + 48234496);   // 16 MiB over x2 [written post-sproj]
  float* gates  = (float*)(WS + 94371840); // 64 KiB
  float* logits = (float*)(WS + 94437376); // 128 KiB
  int* meta     = (int*)(WS + 94568448);
  int* counts   = meta;                    // 8
  int* counts2  = meta + 8;                // 8
  int* offsets  = meta + 16;               // 9
  int* topi     = meta + 32;               // 8192
  float* topw   = (float*)(meta + 8224);   // 8192
  int* tok_idx  = meta + 16416;            // 8192
  float* tok_w  = (float*)(meta + 24608);  // 8192

  hipMemsetAsync(counts, 0, 16 * sizeof(int), stream);

  // weight converts
  cvt_split_k<<<512, 256, 0, stream>>>(Wq, Wq_hi, Wq_lo);
  cvt_split_k<<<128, 256, 0, stream>>>(Wk, Wk_hi, Wk_lo);
  cvt_split_k<<<128, 256, 0, stream>>>(Wv, Wv_hi, Wv_lo);
  cvt_split_k<<<512, 256, 0, stream>>>(Wo, Wo_hi, Wo_lo);
  cvt_bf16_k<<<512, 256, 0, stream>>>(Wsfc, Wsfc_b);
  cvt_bf16_k<<<512, 256, 0, stream>>>(Wsproj, Wsproj_b);
  cvt_bf16_k<<<4096, 256, 0, stream>>>(Wefc, Wefc_b);
  cvt_bf16_k<<<4096, 256, 0, stream>>>(Weproj, Weproj_b);

  // h = rmsnorm(x) split
  rmsnorm_split_k<<<NTOK, 256, 0, stream>>>(x, h_hi, h_lo);
  gates_k<<<64, 256, 0, stream>>>(h_hi, gW, gates);
  // q,k (split gemm + fused rope + head-rms), v (split gemm + fused gate)
  gemm_bf_k<9><<<dim3(8, 32), 256, 0, stream>>>(h_hi, h_lo, Wq_hi, Wq_lo, nullptr, qb, nullptr, 1024, 1024, nullptr, nullptr, nullptr, nullptr, cosb, sinb, nullptr, nullptr);
  gemm_bf_k<9><<<dim3(2, 32), 256, 0, stream>>>(h_hi, h_lo, Wk_hi, Wk_lo, nullptr, kb, nullptr, 256, 1024, nullptr, nullptr, nullptr, nullptr, cosb, sinb, nullptr, nullptr);
  gemm_bf_k<10><<<dim3(2, 32), 256, 0, stream>>>(h_hi, h_lo, Wv_hi, Wv_lo, nullptr, vb, nullptr, 256, 1024, nullptr, nullptr, nullptr, nullptr, nullptr, nullptr, gates, ve);
  // attention -> split y
  attn_mfma_k<<<dim3(TT / 64, 16, 2), 256, 0, stream>>>(qb, kb, vb, y_hi, y_lo, wsz);
  // x2 = x + y @ Wo^T (split)
  gemm_bf_k<6><<<dim3(8, 32), 256, 0, stream>>>(y_hi, y_lo, Wo_hi, Wo_lo, x2, nullptr, x, 1024, 1024, nullptr, nullptr, nullptr, nullptr, nullptr, nullptr, nullptr, nullptr);
  // h2 = rmsnorm(x2) -> bf16 + fp32 router logits
  rmsnorm_logits_k<<<NTOK, 256, 0, stream>>>(x2, h2_b, routerW, logits);
  // shared expert
  gemm_bf_k<3><<<dim3(8, 32), 256, 0, stream>>>(h2_b, nullptr, Wsfc_b, nullptr, nullptr, s1_b, nullptr, 1024, 1024, nullptr, nullptr, nullptr, nullptr, nullptr, nullptr, nullptr, nullptr);
  gemm_bf_k<1><<<dim3(8, 32), 256, 0, stream>>>(s1_b, nullptr, Wsproj_b, nullptr, out, nullptr, x2, 1024, 1024, nullptr, nullptr, nullptr, nullptr, nullptr, nullptr, nullptr, nullptr);
  // router + bucketing
  topk_k<<<16, 256, 0, stream>>>(logits, bias, topi, topw, counts);
  scan_k<<<1, 64, 0, stream>>>(counts, offsets);
  scatter_k<<<16, 256, 0, stream>>>(topi, topw, offsets, counts2, tok_idx, tok_w);
  // routed experts
  gemm_bf_k<4><<<dim3(8, 32, 8), 256, 0, stream>>>(h2_b, nullptr, Wefc_b, nullptr, nullptr, he_b, nullptr, 1024, 1024, offsets, counts, tok_idx, nullptr, nullptr, nullptr, nullptr, nullptr);
  gemm_bf_k<5><<<dim3(8, 32, 8), 256, 0, stream>>>(he_b, nullptr, Weproj_b, nullptr, out, nullptr, nullptr, 1024, 1024, offsets, counts, tok_idx, tok_w, nullptr, nullptr, nullptr, nullptr);
}

// Round 5
// 485.817 us; speedup vs baseline: 5.1072x; 1.1282x over previous
//
#include <hip/hip_runtime.h>

// Problem constants
#define TT 2048
#define CC 1024
#define NTOK 4096
#define EPSF 1.1920929e-07f

typedef unsigned short u16;
typedef short bf16x8 __attribute__((ext_vector_type(8)));
typedef u16 u16x4 __attribute__((ext_vector_type(4)));
typedef float f32x4 __attribute__((ext_vector_type(4)));

__device__ __forceinline__ u16 f2b(float f) {
  union { float f; unsigned u; } v; v.f = f;
  unsigned r = v.u + 0x7FFFu + ((v.u >> 16) & 1u);
  return (u16)(r >> 16);
}
__device__ __forceinline__ float b2f(u16 u) {
  union { unsigned u; float f; } v; v.u = ((unsigned)u) << 16;
  return v.f;
}
__device__ __forceinline__ void gload16(const u16* g, u16* l) {
  __builtin_amdgcn_global_load_lds(
      (const __attribute__((address_space(1))) void*)g,
      (__attribute__((address_space(3))) void*)l, 16, 0, 0);
}
// swizzled LDS fragment read: tile [R rows][64 u16], phys seg = kseg ^ (row&7)
__device__ __forceinline__ bf16x8 ldsf(const u16* s, int row, int kseg) {
  return *(const bf16x8*)(s + (row << 6) + ((kseg ^ (row & 7)) << 3));
}

// ---------------- fused weight converts ----------------
__global__ __launch_bounds__(256) void cvt_split4_k(const float* __restrict__ p0,
                                                    const float* __restrict__ p1,
                                                    const float* __restrict__ p2,
                                                    const float* __restrict__ p3,
                                                    u16* __restrict__ h0, u16* __restrict__ l0,
                                                    u16* __restrict__ h1, u16* __restrict__ l1,
                                                    u16* __restrict__ h2, u16* __restrict__ l2,
                                                    u16* __restrict__ h3, u16* __restrict__ l3) {
  const int sizes[4] = {131072, 32768, 32768, 131072};  // 8-elem chunks
  int seg = blockIdx.y;
  int i = blockIdx.x * 256 + threadIdx.x;
  if (i >= sizes[seg]) return;
  const float* in = seg == 0 ? p0 : seg == 1 ? p1 : seg == 2 ? p2 : p3;
  u16* ho = seg == 0 ? h0 : seg == 1 ? h1 : seg == 2 ? h2 : h3;
  u16* lo = seg == 0 ? l0 : seg == 1 ? l1 : seg == 2 ? l2 : l3;
  i *= 8;
  float v[8];
  *(float4*)v = *(const float4*)(in + i);
  *(float4*)(v + 4) = *(const float4*)(in + i + 4);
  u16 h[8], l[8];
#pragma unroll
  for (int j = 0; j < 8; ++j) {
    h[j] = f2b(v[j]);
    l[j] = f2b(v[j] - b2f(h[j]));
  }
  *(bf16x8*)(ho + i) = *(bf16x8*)h;
  *(bf16x8*)(lo + i) = *(bf16x8*)l;
}

__global__ __launch_bounds__(256) void cvt4_k(const float* __restrict__ p0,
                                              const float* __restrict__ p1,
                                              const float* __restrict__ p2,
                                              const float* __restrict__ p3,
                                              u16* __restrict__ o0, u16* __restrict__ o1,
                                              u16* __restrict__ o2, u16* __restrict__ o3) {
  const int sizes[4] = {131072, 131072, 1048576, 1048576};  // 8-elem chunks
  int seg = blockIdx.y;
  int i = blockIdx.x * 256 + threadIdx.x;
  if (i >= sizes[seg]) return;
  const float* in = seg == 0 ? p0 : seg == 1 ? p1 : seg == 2 ? p2 : p3;
  u16* ou = seg == 0 ? o0 : seg == 1 ? o1 : seg == 2 ? o2 : o3;
  i *= 8;
  float4 a = *(const float4*)(in + i);
  float4 b = *(const float4*)(in + i + 4);
  u16 r[8] = {f2b(a.x), f2b(a.y), f2b(a.z), f2b(a.w),
              f2b(b.x), f2b(b.y), f2b(b.z), f2b(b.w)};
  *(bf16x8*)(ou + i) = *(bf16x8*)r;
}

// ---------------- RMSNorm -> split bf16 (hi/lo) ----------------
__global__ __launch_bounds__(256) void rmsnorm_split_k(const float* __restrict__ in,
                                                       u16* __restrict__ hio,
                                                       u16* __restrict__ loo) {
  const int rowi = blockIdx.x;
  const int t = threadIdx.x;
  float4 v = ((const float4*)(in + (size_t)rowi * CC))[t];
  float ss = v.x * v.x + v.y * v.y + v.z * v.z + v.w * v.w;
#pragma unroll
  for (int off = 32; off; off >>= 1) ss += __shfl_down(ss, off, 64);
  __shared__ float red[4];
  if ((t & 63) == 0) red[t >> 6] = ss;
  __syncthreads();
  float tot = red[0] + red[1] + red[2] + red[3];
  float sc = rsqrtf(tot * (1.0f / CC) + EPSF);
  float o[4] = {v.x * sc, v.y * sc, v.z * sc, v.w * sc};
  u16 h[4], l[4];
#pragma unroll
  for (int j = 0; j < 4; ++j) {
    h[j] = f2b(o[j]);
    l[j] = f2b(o[j] - b2f(h[j]));
  }
  *(u16x4*)(hio + (size_t)rowi * CC + t * 4) = *(u16x4*)h;
  *(u16x4*)(loo + (size_t)rowi * CC + t * 4) = *(u16x4*)l;
}

// ---------------- RMSNorm(x2) -> bf16 h2 + fp32 router logits ----------------
__global__ __launch_bounds__(256) void rmsnorm_logits_k(const float* __restrict__ in,
                                                        u16* __restrict__ b16o,
                                                        const float* __restrict__ rW,
                                                        float* __restrict__ logits) {
  const int rowi = blockIdx.x;
  const int t = threadIdx.x;
  float4 v = ((const float4*)(in + (size_t)rowi * CC))[t];
  float ss = v.x * v.x + v.y * v.y + v.z * v.z + v.w * v.w;
#pragma unroll
  for (int off = 32; off; off >>= 1) ss += __shfl_down(ss, off, 64);
  __shared__ float red[4];
  __shared__ float red2[8][4];
  if ((t & 63) == 0) red[t >> 6] = ss;
  __syncthreads();
  float tot = red[0] + red[1] + red[2] + red[3];
  float sc = rsqrtf(tot * (1.0f / CC) + EPSF);
  float o[4] = {v.x * sc, v.y * sc, v.z * sc, v.w * sc};
  u16 h[4] = {f2b(o[0]), f2b(o[1]), f2b(o[2]), f2b(o[3])};
  *(u16x4*)(b16o + (size_t)rowi * CC + t * 4) = *(u16x4*)h;
  const float* rwp = rW + (t << 2);
  float part[8];
#pragma unroll
  for (int e = 0; e < 8; ++e) {
    const float* w = rwp + (e << 10);
    part[e] = o[0] * w[0] + o[1] * w[1] + o[2] * w[2] + o[3] * w[3];
  }
  const int wid = t >> 6;
#pragma unroll
  for (int e = 0; e < 8; ++e) {
    float p = part[e];
#pragma unroll
    for (int off = 32; off; off >>= 1) p += __shfl_down(p, off, 64);
    if ((t & 63) == 0) red2[e][wid] = p;
  }
  __syncthreads();
  if (t < 8) logits[rowi * 8 + t] = red2[t][0] + red2[t][1] + red2[t][2] + red2[t][3];
}

// ---------------- gates[n][kh] = 2*sigmoid(h[n,:32] @ gW[kh]) ----------------
__global__ __launch_bounds__(256) void gates_k(const u16* __restrict__ hb,
                                               const float* __restrict__ gW,
                                               float* __restrict__ gates) {
  int idx = blockIdx.x * 256 + threadIdx.x;  // token*4 + kh
  int tok = idx >> 2, kh = idx & 3;
  const u16* hr = hb + (size_t)tok * CC;
  const float* gw = gW + (kh << 5);
  float dot = 0.f;
#pragma unroll
  for (int j = 0; j < 32; ++j) dot += b2f(hr[j]) * gw[j];
  gates[idx] = 2.f / (1.f + __expf(-dot));
}

// ---------------- bf16 MFMA GEMM: C[M,N] = A[M,K] @ W[N,K]^T ----------------
// 128x128 tile, BK=64, 4 waves (2x2). MODE:
// 1 plain, f32 out += addv        (shared proj -> out)
// 3 plain, relu^2 bf16 out        (shared fc)
// 4 plain, gathered A, relu^2 bf16 (expert fc)
// 5 plain, gathered rows, w*atomicAdd f32 (expert proj)
// 6 split(3-mfma), f32 out += addv (Wo -> x2)
// 11 split fused QKV: N=1536 col-space; Q->rope+rms, K->rope+rms, V->gate
template <int MODE>
__global__ __launch_bounds__(256) void gemm_bf_k(
    const u16* __restrict__ A, const u16* __restrict__ A2,
    const u16* __restrict__ Wt, const u16* __restrict__ W2,
    const u16* __restrict__ Wk1, const u16* __restrict__ Wk2,
    const u16* __restrict__ Wv1, const u16* __restrict__ Wv2,
    float* __restrict__ Cf, u16* __restrict__ Cb,
    u16* __restrict__ Ck, u16* __restrict__ Cv,
    const float* __restrict__ addv, int N, int K,
    const int* __restrict__ offsets, const int* __restrict__ counts,
    const int* __restrict__ tok_idx, const float* __restrict__ tok_w,
    const float* __restrict__ cosb, const float* __restrict__ sinb,
    const float* __restrict__ gates, const float* __restrict__ vein) {
  constexpr bool SPLIT = (MODE == 6 || MODE == 11);
  constexpr int NS = SPLIT ? 2 : 1;
  __shared__ __align__(16) u16 Asw[NS * 8192];
  __shared__ __align__(16) u16 Bsw[NS * 8192];
  const int t = threadIdx.x;
  const int lane = t & 63;
  const int l15 = lane & 15, hi = lane >> 4;
  const int wave = t >> 6;
  const int wr = wave >> 1, wc = wave & 1;
  const int e = blockIdx.z;
  const int mt = blockIdx.y << 7;
  const int bn = blockIdx.x << 7;
  int base = 0, cnt = 0;
  if (MODE == 4 || MODE == 5) {
    cnt = counts[e];
    if (mt >= cnt) return;
    base = offsets[e];
  }
  const int r8 = t >> 3;
  const int ksg = (t & 7) ^ (r8 & 7);  // inverse-swizzled global k-segment
  const u16* asrc[4];
  const u16* bsrc[4];
  const u16* asrc2[4];
  const u16* bsrc2[4];
  // weight selection
  const u16* W1p = Wt + ((MODE == 4 || MODE == 5) ? ((size_t)e << 20) : (size_t)0);
  const u16* W2p = W2;
  int wrow = bn;
  if (MODE == 11) {
    if (bn >= 1280)      { W1p = Wv1; W2p = Wv2; wrow = bn - 1280; }
    else if (bn >= 1024) { W1p = Wk1; W2p = Wk2; wrow = bn - 1024; }
  }
#pragma unroll
  for (int g = 0; g < 4; ++g) {
    int rl = (g << 5) + r8;
    int arow;
    if (MODE == 4) {
      int rr = mt + rl; if (rr > cnt - 1) rr = cnt - 1;
      arow = tok_idx[base + rr];
    } else if (MODE == 5) {
      int rr = mt + rl; if (rr > cnt - 1) rr = cnt - 1;
      arow = base + rr;
    } else {
      arow = mt + rl;
    }
    size_t ao = (size_t)arow * K + (ksg << 3);
    size_t bo = (size_t)(wrow + rl) * K + (ksg << 3);
    asrc[g] = A + ao;
    bsrc[g] = W1p + bo;
    if (SPLIT) { asrc2[g] = A2 + ao; bsrc2[g] = W2p + bo; }
  }
  f32x4 acc[4][4] = {};
  const int nkt = K >> 6;
  for (int kt = 0; kt < nkt; ++kt) {
    __syncthreads();
    const int ko = kt << 6;
#pragma unroll
    for (int g = 0; g < 4; ++g) {
      int co = ((g << 8) + t) << 3;
      gload16(asrc[g] + ko, &Asw[co]);
      gload16(bsrc[g] + ko, &Bsw[co]);
      if (SPLIT) {
        gload16(asrc2[g] + ko, &Asw[8192 + co]);
        gload16(bsrc2[g] + ko, &Bsw[8192 + co]);
      }
    }
    __syncthreads();
#pragma unroll
    for (int kk = 0; kk < 2; ++kk) {
      bf16x8 ah[4], bh[4];
#pragma unroll
      for (int mi = 0; mi < 4; ++mi)
        ah[mi] = ldsf(Asw, (wr << 6) + (mi << 4) + l15, (kk << 2) + hi);
#pragma unroll
      for (int nj = 0; nj < 4; ++nj)
        bh[nj] = ldsf(Bsw, (wc << 6) + (nj << 4) + l15, (kk << 2) + hi);
#pragma unroll
      for (int mi = 0; mi < 4; ++mi)
#pragma unroll
        for (int nj = 0; nj < 4; ++nj)
          acc[mi][nj] = __builtin_amdgcn_mfma_f32_16x16x32_bf16(ah[mi], bh[nj], acc[mi][nj], 0, 0, 0);
      if (SPLIT) {
        bf16x8 al[4], bl[4];
#pragma unroll
        for (int mi = 0; mi < 4; ++mi)
          al[mi] = ldsf(Asw + 8192, (wr << 6) + (mi << 4) + l15, (kk << 2) + hi);
#pragma unroll
        for (int nj = 0; nj < 4; ++nj)
          bl[nj] = ldsf(Bsw + 8192, (wc << 6) + (nj << 4) + l15, (kk << 2) + hi);
#pragma unroll
        for (int mi = 0; mi < 4; ++mi)
#pragma unroll
          for (int nj = 0; nj < 4; ++nj)
            acc[mi][nj] = __builtin_amdgcn_mfma_f32_16x16x32_bf16(ah[mi], bl[nj], acc[mi][nj], 0, 0, 0);
#pragma unroll
        for (int mi = 0; mi < 4; ++mi)
#pragma unroll
          for (int nj = 0; nj < 4; ++nj)
            acc[mi][nj] = __builtin_amdgcn_mfma_f32_16x16x32_bf16(al[mi], bh[nj], acc[mi][nj], 0, 0, 0);
      }
    }
  }
  // ---- epilogues (C/D layout: col=l15, row=hi*4+r) ----
  if (MODE == 11) {
    const int col0 = bn + (wc << 6);
    if (col0 < 1280) {
      // rope + per-head rmsnorm (Q or K)
      u16* outp = (col0 < 1024) ? Cb : Ck;
      const int stride = (col0 < 1024) ? 1024 : 256;
      const int cbase = (col0 < 1024) ? col0 : (col0 - 1024);
#pragma unroll
      for (int mi = 0; mi < 4; ++mi) {
#pragma unroll
        for (int r = 0; r < 4; ++r) {
          int row = mt + (wr << 6) + (mi << 4) + (hi << 2) + r;
          int tpos = row & (TT - 1);
          const float* cp = cosb + (tpos << 5);
          const float* sp = sinb + (tpos << 5);
          float c0 = cp[l15], s0 = sp[l15];
          float c1 = cp[16 + l15], s1 = sp[16 + l15];
          float a0 = acc[mi][0][r], a1 = acc[mi][1][r];
          float b0 = acc[mi][2][r], b1 = acc[mi][3][r];
          float r00 = a0 * c0 + b0 * s0;
          float r01 = a1 * c1 + b1 * s1;
          float r10 = b0 * c0 - a0 * s0;
          float r11 = b1 * c1 - a1 * s1;
          float ss = r00 * r00 + r01 * r01 + r10 * r10 + r11 * r11;
          ss += __shfl_xor(ss, 1, 64); ss += __shfl_xor(ss, 2, 64);
          ss += __shfl_xor(ss, 4, 64); ss += __shfl_xor(ss, 8, 64);
          float scn = rsqrtf(ss * (1.f / 64.f) + EPSF);
          u16* qp = outp + (size_t)row * stride + cbase;
          qp[l15]      = f2b(r00 * scn);
          qp[16 + l15] = f2b(r01 * scn);
          qp[32 + l15] = f2b(r10 * scn);
          qp[48 + l15] = f2b(r11 * scn);
        }
      }
    } else {
      const int cbase = col0 - 1280;
      const int kvh = cbase >> 6;
#pragma unroll
      for (int mi = 0; mi < 4; ++mi) {
#pragma unroll
        for (int r = 0; r < 4; ++r) {
          int row = mt + (wr << 6) + (mi << 4) + (hi << 2) + r;
          float g = gates[(row << 2) + kvh];
          const float* vep = vein + ((size_t)row << 8) + cbase;
          u16* vp = Cv + ((size_t)row << 8) + cbase;
#pragma unroll
          for (int nj = 0; nj < 4; ++nj) {
            int d = (nj << 4) + l15;
            vp[d] = f2b(acc[mi][nj][r] + g * vep[d]);
          }
        }
      }
    }
    return;
  }
#pragma unroll
  for (int mi = 0; mi < 4; ++mi) {
#pragma unroll
    for (int r = 0; r < 4; ++r) {
      int rl = (wr << 6) + (mi << 4) + (hi << 2) + r;
      if (MODE == 4 || MODE == 5) {
        int rr = mt + rl;
        if (rr >= cnt) continue;
        if (MODE == 4) {
          size_t ro = (size_t)(base + rr) * N;
#pragma unroll
          for (int nj = 0; nj < 4; ++nj) {
            float v = acc[mi][nj][r];
            v = v > 0.f ? v * v : 0.f;
            Cb[ro + bn + (wc << 6) + (nj << 4) + l15] = f2b(v);
          }
        } else {
          int tok = tok_idx[base + rr];
          float w = tok_w[base + rr];
          size_t ro = (size_t)tok * N;
#pragma unroll
          for (int nj = 0; nj < 4; ++nj)
            atomicAdd(&Cf[ro + bn + (wc << 6) + (nj << 4) + l15], acc[mi][nj][r] * w);
        }
      } else {
        size_t ro = (size_t)(mt + rl) * N;
#pragma unroll
        for (int nj = 0; nj < 4; ++nj) {
          int col = bn + (wc << 6) + (nj << 4) + l15;
          float v = acc[mi][nj][r];
          if (MODE == 1 || MODE == 6) {
            Cf[ro + col] = v + addv[ro + col];
          } else {  // MODE 3
            v = v > 0.f ? v * v : 0.f;
            Cb[ro + col] = f2b(v);
          }
        }
      }
    }
  }
}

// ---------------- flash attention, GQA-shared K/V, bf16 MFMA, XOR-swizzled LDS ----------------
// grid = (64 q-tiles of 32 rows, 4 kvh, 2 b), 256 threads = 4 waves.
// Wave w handles head kvh*4+w, q-rows qt*32..+31 (2 fragments of 16).
__global__ __launch_bounds__(256) void attn_mfma_k(const u16* __restrict__ qb,
                                                   const u16* __restrict__ kb,
                                                   const u16* __restrict__ vb,
                                                   u16* __restrict__ yh,
                                                   u16* __restrict__ yl,
                                                   const int* __restrict__ wszp) {
  const int b = blockIdx.z, kvh = blockIdx.y, qt = blockIdx.x;
  const int Wn = *wszp;
  const int t = threadIdx.x;
  const int lane = t & 63, wave = t >> 6;
  const int h = (kvh << 2) + wave;
  const int l15 = lane & 15, hi = lane >> 4;

  __shared__ __align__(16) u16 Klds[64 * 64];     // swizzled [key][d]
  __shared__ __align__(16) u16 Vt[64 * 64];       // swizzled [d][key]
  __shared__ __align__(16) u16 Plds[4][16 * 64];  // per-wave swizzled [qrow][key]

  const int qrow0 = qt << 5;
  bf16x8 aQ[2][2];
#pragma unroll
  for (int f = 0; f < 2; ++f) {
    const u16* qp = qb + ((size_t)((b << 11) + qrow0 + (f << 4) + l15) << 10) + (h << 6) + (hi << 3);
    aQ[f][0] = *(const bf16x8*)qp;
    aQ[f][1] = *(const bf16x8*)(qp + 32);
  }
  f32x4 o[2][4] = {};
  float mrow[2][4], lrow[2][4];
#pragma unroll
  for (int f = 0; f < 2; ++f)
#pragma unroll
    for (int r = 0; r < 4; ++r) { mrow[f][r] = -INFINITY; lrow[f][r] = 0.f; }

  const int ktmax = (qrow0 + 31) >> 6;
  int lo = qrow0 - Wn + 1;
  int kt0 = lo > 0 ? (lo >> 6) : 0;

  const int kr0 = t >> 3, kc = t & 7;     // K staging coords
  const int vkey = t & 63, vd0 = (t >> 6) << 3;  // V staging coords

  for (int kt = kt0; kt <= ktmax; ++kt) {
    __syncthreads();
    // stage K [64 keys][64 d] swizzled, b128 writes
#pragma unroll
    for (int i = 0; i < 2; ++i) {
      int row = kr0 + (i << 5);
      const u16* kp = kb + ((size_t)((b << 11) + (kt << 6) + row) << 8) + (kvh << 6) + (kc << 3);
      *(bf16x8*)&Klds[(row << 6) + ((kc ^ (row & 7)) << 3)] = *(const bf16x8*)kp;
    }
    // stage V transposed [64 d][64 keys] swizzled, scalar b16 writes
#pragma unroll
    for (int i = 0; i < 2; ++i) {
      int dd0 = vd0 + (i << 5);
      const u16* vp = vb + ((size_t)((b << 11) + (kt << 6) + vkey) << 8) + (kvh << 6) + dd0;
      bf16x8 vv = *(const bf16x8*)vp;
#pragma unroll
      for (int j = 0; j < 8; ++j) {
        int d = dd0 + j;
        Vt[(d << 6) + (((vkey >> 3) ^ (d & 7)) << 3) + (vkey & 7)] = (u16)vv[j];
      }
    }
    __syncthreads();

#pragma unroll
    for (int f = 0; f < 2; ++f) {
      const int qfb = qrow0 + (f << 4);
      // QK^T
      float sv[4][4];
#pragma unroll
      for (int kb4 = 0; kb4 < 4; ++kb4) {
        f32x4 S = {0.f, 0.f, 0.f, 0.f};
        bf16x8 B0 = ldsf(Klds, (kb4 << 4) + l15, hi);
        bf16x8 B1 = ldsf(Klds, (kb4 << 4) + l15, 4 + hi);
        S = __builtin_amdgcn_mfma_f32_16x16x32_bf16(aQ[f][0], B0, S, 0, 0, 0);
        S = __builtin_amdgcn_mfma_f32_16x16x32_bf16(aQ[f][1], B1, S, 0, 0, 0);
        int key = (kt << 6) + (kb4 << 4) + l15;
#pragma unroll
        for (int r = 0; r < 4; ++r) {
          int qg = qfb + (hi << 2) + r;
          float val = S[r] * 0.125f;
          sv[kb4][r] = (key <= qg && key > qg - Wn) ? val : -INFINITY;
        }
      }
      // online softmax
      float scl[4], pv[4][4];
#pragma unroll
      for (int r = 0; r < 4; ++r) {
        float mt2 = fmaxf(fmaxf(sv[0][r], sv[1][r]), fmaxf(sv[2][r], sv[3][r]));
        mt2 = fmaxf(mt2, __shfl_xor(mt2, 1, 64));
        mt2 = fmaxf(mt2, __shfl_xor(mt2, 2, 64));
        mt2 = fmaxf(mt2, __shfl_xor(mt2, 4, 64));
        mt2 = fmaxf(mt2, __shfl_xor(mt2, 8, 64));
        float mn = fmaxf(mrow[f][r], mt2);
        float sc = (mrow[f][r] > -INFINITY) ? __expf(mrow[f][r] - mn) : 0.f;
        float rs = 0.f;
#pragma unroll
        for (int kb4 = 0; kb4 < 4; ++kb4) {
          float p = (sv[kb4][r] > -INFINITY) ? __expf(sv[kb4][r] - mn) : 0.f;
          pv[kb4][r] = p;
          rs += p;
        }
        rs += __shfl_xor(rs, 1, 64);
        rs += __shfl_xor(rs, 2, 64);
        rs += __shfl_xor(rs, 4, 64);
        rs += __shfl_xor(rs, 8, 64);
        mrow[f][r] = mn;
        lrow[f][r] = lrow[f][r] * sc + rs;
        scl[r] = sc;
      }
      // P -> wave-local swizzled LDS
#pragma unroll
      for (int kb4 = 0; kb4 < 4; ++kb4)
#pragma unroll
        for (int r = 0; r < 4; ++r) {
          int row16 = (hi << 2) + r;
          int seg = (kb4 << 1) + (l15 >> 3);
          Plds[wave][(row16 << 6) + ((seg ^ (row16 & 7)) << 3) + (l15 & 7)] = f2b(pv[kb4][r]);
        }
      // rescale O
#pragma unroll
      for (int df = 0; df < 4; ++df) {
        f32x4 t4 = o[f][df];
        t4[0] *= scl[0]; t4[1] *= scl[1]; t4[2] *= scl[2]; t4[3] *= scl[3];
        o[f][df] = t4;
      }
      // PV
#pragma unroll
      for (int ks = 0; ks < 2; ++ks) {
        bf16x8 Ap = ldsf(Plds[wave], l15, (ks << 2) + hi);
#pragma unroll
        for (int df = 0; df < 4; ++df) {
          bf16x8 Bv = ldsf(Vt, (df << 4) + l15, (ks << 2) + hi);
          o[f][df] = __builtin_amdgcn_mfma_f32_16x16x32_bf16(Ap, Bv, o[f][df], 0, 0, 0);
        }
      }
    }
  }

#pragma unroll
  for (int f = 0; f < 2; ++f) {
    float inv[4];
#pragma unroll
    for (int r = 0; r < 4; ++r) inv[r] = lrow[f][r] > 0.f ? 1.f / lrow[f][r] : 0.f;
#pragma unroll
    for (int r = 0; r < 4; ++r) {
      size_t rbase = ((size_t)((b << 11) + qrow0 + (f << 4) + (hi << 2) + r) << 10) + (h << 6) + l15;
#pragma unroll
      for (int df = 0; df < 4; ++df) {
        float fo = o[f][df][r] * inv[r];
        u16 hv = f2b(fo);
        yh[rbase + (df << 4)] = hv;
        yl[rbase + (df << 4)] = f2b(fo - b2f(hv));
      }
    }
  }
}

// ---------------- top-2 router from precomputed logits ----------------
__global__ __launch_bounds__(256) void topk_k(const float* __restrict__ logits,
                                              const float* __restrict__ bias,
                                              int* __restrict__ topi,
                                              float* __restrict__ topw,
                                              int* __restrict__ counts) {
  int n = blockIdx.x * 256 + threadIdx.x;
  if (n >= NTOK) return;
  float sc[8], sel[8];
#pragma unroll
  for (int e2 = 0; e2 < 8; ++e2) {
    float sg = 1.f / (1.f + __expf(-logits[n * 8 + e2]));
    sc[e2] = sg;
    sel[e2] = sg + bias[e2];
  }
  int i1 = 0; float b1 = sel[0];
#pragma unroll
  for (int j = 1; j < 8; ++j) if (sel[j] > b1) { b1 = sel[j]; i1 = j; }
  int i2 = -1; float b2 = -INFINITY;
#pragma unroll
  for (int j = 0; j < 8; ++j) if (j != i1 && sel[j] > b2) { b2 = sel[j]; i2 = j; }
  float w1 = sc[i1], w2 = sc[i2];
  float invs = 1.f / (w1 + w2 + 1e-20f);
  topi[n * 2] = i1; topi[n * 2 + 1] = i2;
  topw[n * 2] = w1 * invs; topw[n * 2 + 1] = w2 * invs;
  atomicAdd(&counts[i1], 1);
  atomicAdd(&counts[i2], 1);
}

__global__ void scan_k(const int* __restrict__ counts, int* __restrict__ offsets) {
  if (threadIdx.x == 0 && blockIdx.x == 0) {
    int s = 0;
    for (int e2 = 0; e2 < 8; ++e2) { offsets[e2] = s; s += counts[e2]; }
    offsets[8] = s;
  }
}

__global__ __launch_bounds__(256) void scatter_k(const int* __restrict__ topi,
                                                 const float* __restrict__ topw,
                                                 const int* __restrict__ offsets,
                                                 int* __restrict__ counts2,
                                                 int* __restrict__ tok_idx,
                                                 float* __restrict__ tok_w) {
  int n = blockIdx.x * 256 + threadIdx.x;
  if (n >= NTOK) return;
  for (int kk = 0; kk < 2; ++kk) {
    int e2 = topi[n * 2 + kk];
    int slot = atomicAdd(&counts2[e2], 1);
    int p = offsets[e2] + slot;
    tok_idx[p] = n;
    tok_w[p] = topw[n * 2 + kk];
  }
}

extern "C" void kernel_launch(void* const* d_in, const int* in_sizes, int n_in,
                              void* d_out, int out_size, void* d_ws, size_t ws_size,
                              hipStream_t stream) {
  const float* x = (const float*)d_in[0];
  const float* ve = (const float*)d_in[1];
  const float* cosb = (const float*)d_in[2];
  const float* sinb = (const float*)d_in[3];
  const float* Wq = (const float*)d_in[4];
  const float* Wk = (const float*)d_in[5];
  const float* Wv = (const float*)d_in[6];
  const float* Wo = (const float*)d_in[7];
  const float* gW = (const float*)d_in[8];
  const float* routerW = (const float*)d_in[9];
  const float* bias = (const float*)d_in[10];
  const float* Wsfc = (const float*)d_in[11];
  const float* Wsproj = (const float*)d_in[12];
  const float* Wefc = (const float*)d_in[13];
  const float* Weproj = (const float*)d_in[14];
  const int* wsz = (const int*)d_in[15];
  float* out = (float*)d_out;
  char* WS = (char*)d_ws;

  // ---- workspace layout (byte offsets), peak ~90.7 MiB ----
  u16* Wefc_b   = (u16*)(WS + 0);          // 16 MiB
  u16* Weproj_b = (u16*)(WS + 16777216);   // 16 MiB
  u16* Wsfc_b   = (u16*)(WS + 33554432);   // 2 MiB
  u16* Wsproj_b = (u16*)(WS + 35651584);   // 2 MiB
  u16* Wq_hi    = (u16*)(WS + 37748736);   // 2 MiB
  u16* Wq_lo    = (u16*)(WS + 39845888);   // 2 MiB
  u16* Wk_hi    = (u16*)(WS + 41943040);   // 0.5 MiB
  u16* Wk_lo    = (u16*)(WS + 42467328);   // 0.5 MiB
  u16* Wv_hi    = (u16*)(WS + 42991616);   // 0.5 MiB
  u16* Wv_lo    = (u16*)(WS + 43515904);   // 0.5 MiB
  u16* Wo_hi    = (u16*)(WS + 44040192);   // 2 MiB
  u16* Wo_lo    = (u16*)(WS + 46137344);   // 2 MiB
  u16* h_hi     = (u16*)(WS + 48234496);   // 8 MiB [dead after gates+QKV]
  u16* h_lo     = (u16*)(WS + 56623104);   // 8 MiB [dead after QKV]
  u16* qb       = (u16*)(WS + 65011712);   // 8 MiB [dead after attn]
  u16* kb       = (u16*)(WS + 73400320);   // 2 MiB [dead after attn]
  u16* vb       = (u16*)(WS + 75497472);   // 2 MiB [dead after attn]
  u16* y_hi     = (u16*)(WS + 77594624);   // 8 MiB [dead after Wo gemm]
  u16* y_lo     = (u16*)(WS + 85983232);   // 8 MiB [dead after Wo gemm]
  float* x2     = (float*)(WS + 48234496); // 16 MiB over h_hi+h_lo [written post-attn]
  u16* h2_b     = (u16*)(WS + 65011712);   // 8 MiB over qb [written post-Wo]
  u16* s1_b     = (u16*)(WS + 77594624);   // 8 MiB over y_hi [written post-Wo]
  u16* he_b     = (u16*)(WS + 48234496);   // 16 MiB over x2 [written post-sproj]
  float* gates  = (float*)(WS + 94371840); // 64 KiB
  float* logits = (float*)(WS + 94437376); // 128 KiB
  int* meta     = (int*)(WS + 94568448);
  int* counts   = meta;
  int* counts2  = meta + 8;
  int* offsets  = meta + 16;
  int* topi     = meta + 32;
  float* topw   = (float*)(meta + 8224);
  int* tok_idx  = meta + 16416;
  float* tok_w  = (float*)(meta + 24608);

  hipMemsetAsync(counts, 0, 16 * sizeof(int), stream);

  // fused weight converts
  cvt_split4_k<<<dim3(512, 4), 256, 0, stream>>>(Wq, Wk, Wv, Wo,
      Wq_hi, Wq_lo, Wk_hi, Wk_lo, Wv_hi, Wv_lo, Wo_hi, Wo_lo);
  cvt4_k<<<dim3(4096, 4), 256, 0, stream>>>(Wsfc, Wsproj, Wefc, Weproj,
      Wsfc_b, Wsproj_b, Wefc_b, Weproj_b);

  // h = rmsnorm(x) split; gates
  rmsnorm_split_k<<<NTOK, 256, 0, stream>>>(x, h_hi, h_lo);
  gates_k<<<64, 256, 0, stream>>>(h_hi, gW, gates);
  // fused QKV split gemm (N=1536) with per-head epilogues
  gemm_bf_k<11><<<dim3(12, 32), 256, 0, stream>>>(
      h_hi, h_lo, Wq_hi, Wq_lo, Wk_hi, Wk_lo, Wv_hi, Wv_lo,
      nullptr, qb, kb, vb, nullptr, 1536, 1024,
      nullptr, nullptr, nullptr, nullptr, cosb, sinb, gates, ve);
  // attention -> split y
  attn_mfma_k<<<dim3(64, 4, 2), 256, 0, stream>>>(qb, kb, vb, y_hi, y_lo, wsz);
  // x2 = x + y @ Wo^T (split)
  gemm_bf_k<6><<<dim3(8, 32), 256, 0, stream>>>(
      y_hi, y_lo, Wo_hi, Wo_lo, nullptr, nullptr, nullptr, nullptr,
      x2, nullptr, nullptr, nullptr, x, 1024, 1024,
      nullptr, nullptr, nullptr, nullptr, nullptr, nullptr, nullptr, nullptr);
  // h2 = rmsnorm(x2) -> bf16 + fp32 router logits
  rmsnorm_logits_k<<<NTOK, 256, 0, stream>>>(x2, h2_b, routerW, logits);
  // shared expert
  gemm_bf_k<3><<<dim3(8, 32), 256, 0, stream>>>(
      h2_b, nullptr, Wsfc_b, nullptr, nullptr, nullptr, nullptr, nullptr,
      nullptr, s1_b, nullptr, nullptr, nullptr, 1024, 1024,
      nullptr, nullptr, nullptr, nullptr, nullptr, nullptr, nullptr, nullptr);
  gemm_bf_k<1><<<dim3(8, 32), 256, 0, stream>>>(
      s1_b, nullptr, Wsproj_b, nullptr, nullptr, nullptr, nullptr, nullptr,
      out, nullptr, nullptr, nullptr, x2, 1024, 1024,
      nullptr, nullptr, nullptr, nullptr, nullptr, nullptr, nullptr, nullptr);
  // router + bucketing
  topk_k<<<16, 256, 0, stream>>>(logits, bias, topi, topw, counts);
  scan_k<<<1, 64, 0, stream>>>(counts, offsets);
  scatter_k<<<16, 256, 0, stream>>>(topi, topw, offsets, counts2, tok_idx, tok_w);
  // routed experts
  gemm_bf_k<4><<<dim3(8, 32, 8), 256, 0, stream>>>(
      h2_b, nullptr, Wefc_b, nullptr, nullptr, nullptr, nullptr, nullptr,
      nullptr, he_b, nullptr, nullptr, nullptr, 1024, 1024,
      offsets, counts, tok_idx, nullptr, nullptr, nullptr, nullptr, nullptr);
  gemm_bf_k<5><<<dim3(8, 32, 8), 256, 0, stream>>>(
      he_b, nullptr, Weproj_b, nullptr, nullptr, nullptr, nullptr, nullptr,
      out, nullptr, nullptr, nullptr, nullptr, 1024, 1024,
      offsets, counts, tok_idx, tok_w, nullptr, nullptr, nullptr, nullptr);
}

// Round 6
// 440.123 us; speedup vs baseline: 5.6374x; 1.1038x over previous
//
#include <hip/hip_runtime.h>

// Problem constants
#define TT 2048
#define CC 1024
#define NTOK 4096
#define EPSF 1.1920929e-07f

typedef unsigned short u16;
typedef short bf16x8 __attribute__((ext_vector_type(8)));
typedef u16 u16x4 __attribute__((ext_vector_type(4)));
typedef float f32x4 __attribute__((ext_vector_type(4)));

__device__ __forceinline__ u16 f2b(float f) {
  union { float f; unsigned u; } v; v.f = f;
  unsigned r = v.u + 0x7FFFu + ((v.u >> 16) & 1u);
  return (u16)(r >> 16);
}
__device__ __forceinline__ float b2f(u16 u) {
  union { unsigned u; float f; } v; v.u = ((unsigned)u) << 16;
  return v.f;
}
__device__ __forceinline__ void gload16(const u16* g, u16* l) {
  __builtin_amdgcn_global_load_lds(
      (const __attribute__((address_space(1))) void*)g,
      (__attribute__((address_space(3))) void*)l, 16, 0, 0);
}
// swizzled LDS fragment read: tile [R rows][64 u16], phys seg = kseg ^ (row&7)
__device__ __forceinline__ bf16x8 ldsf(const u16* s, int row, int kseg) {
  return *(const bf16x8*)(s + (row << 6) + ((kseg ^ (row & 7)) << 3));
}

// ---------------- fused weight converts ----------------
__global__ __launch_bounds__(256) void cvt_split4_k(const float* __restrict__ p0,
                                                    const float* __restrict__ p1,
                                                    const float* __restrict__ p2,
                                                    const float* __restrict__ p3,
                                                    u16* __restrict__ h0, u16* __restrict__ l0,
                                                    u16* __restrict__ h1, u16* __restrict__ l1,
                                                    u16* __restrict__ h2, u16* __restrict__ l2,
                                                    u16* __restrict__ h3, u16* __restrict__ l3) {
  const int sizes[4] = {131072, 32768, 32768, 131072};  // 8-elem chunks
  int seg = blockIdx.y;
  int i = blockIdx.x * 256 + threadIdx.x;
  if (i >= sizes[seg]) return;
  const float* in = seg == 0 ? p0 : seg == 1 ? p1 : seg == 2 ? p2 : p3;
  u16* ho = seg == 0 ? h0 : seg == 1 ? h1 : seg == 2 ? h2 : h3;
  u16* lo = seg == 0 ? l0 : seg == 1 ? l1 : seg == 2 ? l2 : l3;
  i *= 8;
  float v[8];
  *(float4*)v = *(const float4*)(in + i);
  *(float4*)(v + 4) = *(const float4*)(in + i + 4);
  u16 h[8], l[8];
#pragma unroll
  for (int j = 0; j < 8; ++j) {
    h[j] = f2b(v[j]);
    l[j] = f2b(v[j] - b2f(h[j]));
  }
  *(bf16x8*)(ho + i) = *(bf16x8*)h;
  *(bf16x8*)(lo + i) = *(bf16x8*)l;
}

__global__ __launch_bounds__(256) void cvt4_k(const float* __restrict__ p0,
                                              const float* __restrict__ p1,
                                              const float* __restrict__ p2,
                                              const float* __restrict__ p3,
                                              u16* __restrict__ o0, u16* __restrict__ o1,
                                              u16* __restrict__ o2, u16* __restrict__ o3) {
  const int sizes[4] = {131072, 131072, 1048576, 1048576};  // 8-elem chunks
  int seg = blockIdx.y;
  int i = blockIdx.x * 256 + threadIdx.x;
  if (i >= sizes[seg]) return;
  const float* in = seg == 0 ? p0 : seg == 1 ? p1 : seg == 2 ? p2 : p3;
  u16* ou = seg == 0 ? o0 : seg == 1 ? o1 : seg == 2 ? o2 : o3;
  i *= 8;
  float4 a = *(const float4*)(in + i);
  float4 b = *(const float4*)(in + i + 4);
  u16 r[8] = {f2b(a.x), f2b(a.y), f2b(a.z), f2b(a.w),
              f2b(b.x), f2b(b.y), f2b(b.z), f2b(b.w)};
  *(bf16x8*)(ou + i) = *(bf16x8*)r;
}

// ---------------- RMSNorm -> split bf16 (hi/lo) + fused ve-gates ----------------
__global__ __launch_bounds__(256) void rmsnorm_split_k(const float* __restrict__ in,
                                                       u16* __restrict__ hio,
                                                       u16* __restrict__ loo,
                                                       const float* __restrict__ gW,
                                                       float* __restrict__ gates) {
  const int rowi = blockIdx.x;
  const int t = threadIdx.x;
  float4 v = ((const float4*)(in + (size_t)rowi * CC))[t];
  float ss = v.x * v.x + v.y * v.y + v.z * v.z + v.w * v.w;
#pragma unroll
  for (int off = 32; off; off >>= 1) ss += __shfl_down(ss, off, 64);
  __shared__ float red[4];
  __shared__ float hshare[32];
  if ((t & 63) == 0) red[t >> 6] = ss;
  __syncthreads();
  float tot = red[0] + red[1] + red[2] + red[3];
  float sc = rsqrtf(tot * (1.0f / CC) + EPSF);
  float o[4] = {v.x * sc, v.y * sc, v.z * sc, v.w * sc};
  u16 h[4], l[4];
#pragma unroll
  for (int j = 0; j < 4; ++j) {
    h[j] = f2b(o[j]);
    l[j] = f2b(o[j] - b2f(h[j]));
  }
  *(u16x4*)(hio + (size_t)rowi * CC + t * 4) = *(u16x4*)h;
  *(u16x4*)(loo + (size_t)rowi * CC + t * 4) = *(u16x4*)l;
  if (t < 8) *(float4*)&hshare[t << 2] = *(float4*)o;
  __syncthreads();
  if (t < 4) {
    const float* gw = gW + (t << 5);
    float dot = 0.f;
#pragma unroll
    for (int j = 0; j < 32; ++j) dot += hshare[j] * gw[j];
    gates[(rowi << 2) + t] = 2.f / (1.f + __expf(-dot));
  }
}

// ---------------- RMSNorm(x2) -> bf16 h2 + fp32 router logits ----------------
__global__ __launch_bounds__(256) void rmsnorm_logits_k(const float* __restrict__ in,
                                                        u16* __restrict__ b16o,
                                                        const float* __restrict__ rW,
                                                        float* __restrict__ logits) {
  const int rowi = blockIdx.x;
  const int t = threadIdx.x;
  float4 v = ((const float4*)(in + (size_t)rowi * CC))[t];
  float ss = v.x * v.x + v.y * v.y + v.z * v.z + v.w * v.w;
#pragma unroll
  for (int off = 32; off; off >>= 1) ss += __shfl_down(ss, off, 64);
  __shared__ float red[4];
  __shared__ float red2[8][4];
  if ((t & 63) == 0) red[t >> 6] = ss;
  __syncthreads();
  float tot = red[0] + red[1] + red[2] + red[3];
  float sc = rsqrtf(tot * (1.0f / CC) + EPSF);
  float o[4] = {v.x * sc, v.y * sc, v.z * sc, v.w * sc};
  u16 h[4] = {f2b(o[0]), f2b(o[1]), f2b(o[2]), f2b(o[3])};
  *(u16x4*)(b16o + (size_t)rowi * CC + t * 4) = *(u16x4*)h;
  const float* rwp = rW + (t << 2);
  float part[8];
#pragma unroll
  for (int e = 0; e < 8; ++e) {
    const float* w = rwp + (e << 10);
    part[e] = o[0] * w[0] + o[1] * w[1] + o[2] * w[2] + o[3] * w[3];
  }
  const int wid = t >> 6;
#pragma unroll
  for (int e = 0; e < 8; ++e) {
    float p = part[e];
#pragma unroll
    for (int off = 32; off; off >>= 1) p += __shfl_down(p, off, 64);
    if ((t & 63) == 0) red2[e][wid] = p;
  }
  __syncthreads();
  if (t < 8) logits[rowi * 8 + t] = red2[t][0] + red2[t][1] + red2[t][2] + red2[t][3];
}

// ---------------- bf16 MFMA GEMM: C[M,N] = A[M,K] @ W[N,K]^T ----------------
// 128x128 tile, BK=64, 4 waves (2x2). MODE:
// 1 plain, f32 out += addv        (shared proj -> out)
// 3 plain, relu^2 bf16 out        (shared fc)
// 4 plain, gathered A, relu^2 bf16 (expert fc)
// 5 plain, gathered rows, w*atomicAdd f32 (expert proj)
// 6 split(3-mfma), f32 out += addv (Wo -> x2)
// 11 split fused QKV: N=1536 col-space; Q->rope+rms, K->rope+rms, V->gate (transposed store)
template <int MODE>
__global__ __launch_bounds__(256) void gemm_bf_k(
    const u16* __restrict__ A, const u16* __restrict__ A2,
    const u16* __restrict__ Wt, const u16* __restrict__ W2,
    const u16* __restrict__ Wk1, const u16* __restrict__ Wk2,
    const u16* __restrict__ Wv1, const u16* __restrict__ Wv2,
    float* __restrict__ Cf, u16* __restrict__ Cb,
    u16* __restrict__ Ck, u16* __restrict__ Cv,
    const float* __restrict__ addv, int N, int K,
    const int* __restrict__ offsets, const int* __restrict__ counts,
    const int* __restrict__ tok_idx, const float* __restrict__ tok_w,
    const float* __restrict__ cosb, const float* __restrict__ sinb,
    const float* __restrict__ gates, const float* __restrict__ vein) {
  constexpr bool SPLIT = (MODE == 6 || MODE == 11);
  constexpr int NS = SPLIT ? 2 : 1;
  __shared__ __align__(16) u16 Asw[NS * 8192];
  __shared__ __align__(16) u16 Bsw[NS * 8192];
  const int t = threadIdx.x;
  const int lane = t & 63;
  const int l15 = lane & 15, hi = lane >> 4;
  const int wave = t >> 6;
  const int wr = wave >> 1, wc = wave & 1;
  const int e = blockIdx.z;
  const int mt = blockIdx.y << 7;
  const int bn = blockIdx.x << 7;
  int base = 0, cnt = 0;
  if (MODE == 4 || MODE == 5) {
    cnt = counts[e];
    if (mt >= cnt) return;
    base = offsets[e];
  }
  const int r8 = t >> 3;
  const int ksg = (t & 7) ^ (r8 & 7);  // inverse-swizzled global k-segment
  const u16* asrc[4];
  const u16* bsrc[4];
  const u16* asrc2[4];
  const u16* bsrc2[4];
  // weight selection
  const u16* W1p = Wt + ((MODE == 4 || MODE == 5) ? ((size_t)e << 20) : (size_t)0);
  const u16* W2p = W2;
  int wrow = bn;
  if (MODE == 11) {
    if (bn >= 1280)      { W1p = Wv1; W2p = Wv2; wrow = bn - 1280; }
    else if (bn >= 1024) { W1p = Wk1; W2p = Wk2; wrow = bn - 1024; }
  }
#pragma unroll
  for (int g = 0; g < 4; ++g) {
    int rl = (g << 5) + r8;
    int arow;
    if (MODE == 4) {
      int rr = mt + rl; if (rr > cnt - 1) rr = cnt - 1;
      arow = tok_idx[base + rr];
    } else if (MODE == 5) {
      int rr = mt + rl; if (rr > cnt - 1) rr = cnt - 1;
      arow = base + rr;
    } else {
      arow = mt + rl;
    }
    size_t ao = (size_t)arow * K + (ksg << 3);
    size_t bo = (size_t)(wrow + rl) * K + (ksg << 3);
    asrc[g] = A + ao;
    bsrc[g] = W1p + bo;
    if (SPLIT) { asrc2[g] = A2 + ao; bsrc2[g] = W2p + bo; }
  }
  f32x4 acc[4][4] = {};
  const int nkt = K >> 6;
  for (int kt = 0; kt < nkt; ++kt) {
    __syncthreads();
    const int ko = kt << 6;
#pragma unroll
    for (int g = 0; g < 4; ++g) {
      int co = ((g << 8) + t) << 3;
      gload16(asrc[g] + ko, &Asw[co]);
      gload16(bsrc[g] + ko, &Bsw[co]);
      if (SPLIT) {
        gload16(asrc2[g] + ko, &Asw[8192 + co]);
        gload16(bsrc2[g] + ko, &Bsw[8192 + co]);
      }
    }
    __syncthreads();
#pragma unroll
    for (int kk = 0; kk < 2; ++kk) {
      bf16x8 ah[4], bh[4];
#pragma unroll
      for (int mi = 0; mi < 4; ++mi)
        ah[mi] = ldsf(Asw, (wr << 6) + (mi << 4) + l15, (kk << 2) + hi);
#pragma unroll
      for (int nj = 0; nj < 4; ++nj)
        bh[nj] = ldsf(Bsw, (wc << 6) + (nj << 4) + l15, (kk << 2) + hi);
#pragma unroll
      for (int mi = 0; mi < 4; ++mi)
#pragma unroll
        for (int nj = 0; nj < 4; ++nj)
          acc[mi][nj] = __builtin_amdgcn_mfma_f32_16x16x32_bf16(ah[mi], bh[nj], acc[mi][nj], 0, 0, 0);
      if (SPLIT) {
        bf16x8 al[4], bl[4];
#pragma unroll
        for (int mi = 0; mi < 4; ++mi)
          al[mi] = ldsf(Asw + 8192, (wr << 6) + (mi << 4) + l15, (kk << 2) + hi);
#pragma unroll
        for (int nj = 0; nj < 4; ++nj)
          bl[nj] = ldsf(Bsw + 8192, (wc << 6) + (nj << 4) + l15, (kk << 2) + hi);
#pragma unroll
        for (int mi = 0; mi < 4; ++mi)
#pragma unroll
          for (int nj = 0; nj < 4; ++nj)
            acc[mi][nj] = __builtin_amdgcn_mfma_f32_16x16x32_bf16(ah[mi], bl[nj], acc[mi][nj], 0, 0, 0);
#pragma unroll
        for (int mi = 0; mi < 4; ++mi)
#pragma unroll
          for (int nj = 0; nj < 4; ++nj)
            acc[mi][nj] = __builtin_amdgcn_mfma_f32_16x16x32_bf16(al[mi], bh[nj], acc[mi][nj], 0, 0, 0);
      }
    }
  }
  // ---- epilogues (C/D layout: col=l15, row=hi*4+r) ----
  if (MODE == 11) {
    const int col0 = bn + (wc << 6);
    if (col0 < 1280) {
      // rope + per-head rmsnorm (Q or K)
      u16* outp = (col0 < 1024) ? Cb : Ck;
      const int stride = (col0 < 1024) ? 1024 : 256;
      const int cbase = (col0 < 1024) ? col0 : (col0 - 1024);
#pragma unroll
      for (int mi = 0; mi < 4; ++mi) {
#pragma unroll
        for (int r = 0; r < 4; ++r) {
          int row = mt + (wr << 6) + (mi << 4) + (hi << 2) + r;
          int tpos = row & (TT - 1);
          const float* cp = cosb + (tpos << 5);
          const float* sp = sinb + (tpos << 5);
          float c0 = cp[l15], s0 = sp[l15];
          float c1 = cp[16 + l15], s1 = sp[16 + l15];
          float a0 = acc[mi][0][r], a1 = acc[mi][1][r];
          float b0 = acc[mi][2][r], b1 = acc[mi][3][r];
          float r00 = a0 * c0 + b0 * s0;
          float r01 = a1 * c1 + b1 * s1;
          float r10 = b0 * c0 - a0 * s0;
          float r11 = b1 * c1 - a1 * s1;
          float ss = r00 * r00 + r01 * r01 + r10 * r10 + r11 * r11;
          ss += __shfl_xor(ss, 1, 64); ss += __shfl_xor(ss, 2, 64);
          ss += __shfl_xor(ss, 4, 64); ss += __shfl_xor(ss, 8, 64);
          float scn = rsqrtf(ss * (1.f / 64.f) + EPSF);
          u16* qp = outp + (size_t)row * stride + cbase;
          qp[l15]      = f2b(r00 * scn);
          qp[16 + l15] = f2b(r01 * scn);
          qp[32 + l15] = f2b(r10 * scn);
          qp[48 + l15] = f2b(r11 * scn);
        }
      }
    } else {
      // V: gate epilogue, store TRANSPOSED: Cv[((b*4+kvh)*64 + d)*2048 + tok_in_b]
      const int cbase = col0 - 1280;
      const int kvh = cbase >> 6;
#pragma unroll
      for (int mi = 0; mi < 4; ++mi) {
#pragma unroll
        for (int r = 0; r < 4; ++r) {
          int row = mt + (wr << 6) + (mi << 4) + (hi << 2) + r;
          float g = gates[(row << 2) + kvh];
          const float* vep = vein + ((size_t)row << 8) + cbase;
          size_t vb_base = ((size_t)(((row >> 11) << 2) + kvh) << 17) + (row & (TT - 1));
#pragma unroll
          for (int nj = 0; nj < 4; ++nj) {
            int d = (nj << 4) + l15;
            Cv[vb_base + ((size_t)d << 11)] = f2b(acc[mi][nj][r] + g * vep[d]);
          }
        }
      }
    }
    return;
  }
#pragma unroll
  for (int mi = 0; mi < 4; ++mi) {
#pragma unroll
    for (int r = 0; r < 4; ++r) {
      int rl = (wr << 6) + (mi << 4) + (hi << 2) + r;
      if (MODE == 4 || MODE == 5) {
        int rr = mt + rl;
        if (rr >= cnt) continue;
        if (MODE == 4) {
          size_t ro = (size_t)(base + rr) * N;
#pragma unroll
          for (int nj = 0; nj < 4; ++nj) {
            float v = acc[mi][nj][r];
            v = v > 0.f ? v * v : 0.f;
            Cb[ro + bn + (wc << 6) + (nj << 4) + l15] = f2b(v);
          }
        } else {
          int tok = tok_idx[base + rr];
          float w = tok_w[base + rr];
          size_t ro = (size_t)tok * N;
#pragma unroll
          for (int nj = 0; nj < 4; ++nj)
            atomicAdd(&Cf[ro + bn + (wc << 6) + (nj << 4) + l15], acc[mi][nj][r] * w);
        }
      } else {
        size_t ro = (size_t)(mt + rl) * N;
#pragma unroll
        for (int nj = 0; nj < 4; ++nj) {
          int col = bn + (wc << 6) + (nj << 4) + l15;
          float v = acc[mi][nj][r];
          if (MODE == 1 || MODE == 6) {
            Cf[ro + col] = v + addv[ro + col];
          } else {  // MODE 3
            v = v > 0.f ? v * v : 0.f;
            Cb[ro + col] = f2b(v);
          }
        }
      }
    }
  }
}

// ---------------- flash attention, GQA-shared K/V, 16-row q-frags, swizzled LDS ----------------
// grid = (128 q-frags, 4 kvh, 2 b), 256 threads = 4 waves; wave w = head kvh*4+w.
// V comes pre-transposed in global: vbT[((b*4+kvh)*64 + d)*2048 + key].
__global__ __launch_bounds__(256) void attn_mfma_k(const u16* __restrict__ qb,
                                                   const u16* __restrict__ kb,
                                                   const u16* __restrict__ vbT,
                                                   u16* __restrict__ yh,
                                                   u16* __restrict__ yl,
                                                   const int* __restrict__ wszp) {
  const int b = blockIdx.z, kvh = blockIdx.y, qf = blockIdx.x;
  const int Wn = *wszp;
  const int t = threadIdx.x;
  const int lane = t & 63, wave = t >> 6;
  const int h = (kvh << 2) + wave;
  const int l15 = lane & 15, hi = lane >> 4;

  __shared__ __align__(16) u16 Klds[64 * 64];     // swizzled [key][d]
  __shared__ __align__(16) u16 Vt[64 * 64];       // swizzled [d][key]
  __shared__ __align__(16) u16 Plds[4][16 * 64];  // per-wave swizzled [qrow][key]

  const int qrow0 = qf << 4;
  bf16x8 aQ0, aQ1;
  {
    const u16* qp = qb + ((size_t)((b << 11) + qrow0 + l15) << 10) + (h << 6) + (hi << 3);
    aQ0 = *(const bf16x8*)qp;
    aQ1 = *(const bf16x8*)(qp + 32);
  }
  f32x4 o[4] = {};
  float mrow[4] = {-INFINITY, -INFINITY, -INFINITY, -INFINITY};
  float lrow[4] = {0.f, 0.f, 0.f, 0.f};

  const int ktmax = (qrow0 + 15) >> 6;
  int lo = qrow0 - Wn + 1;
  int kt0 = lo > 0 ? (lo >> 6) : 0;

  const int kr0 = t >> 3, kc = t & 7;  // staging coords (row 0..31, 8-elem col chunk)
  const u16* vbase = vbT + ((size_t)((b << 2) + kvh) << 17);

  for (int kt = kt0; kt <= ktmax; ++kt) {
    __syncthreads();
#pragma unroll
    for (int i = 0; i < 2; ++i) {
      int row = kr0 + (i << 5);
      // K natural rows -> swizzled LDS
      const u16* kp = kb + ((size_t)((b << 11) + (kt << 6) + row) << 8) + (kvh << 6) + (kc << 3);
      *(bf16x8*)&Klds[(row << 6) + ((kc ^ (row & 7)) << 3)] = *(const bf16x8*)kp;
      // V transposed rows (row = d) -> swizzled LDS
      const u16* vp = vbase + ((size_t)row << 11) + (kt << 6) + (kc << 3);
      *(bf16x8*)&Vt[(row << 6) + ((kc ^ (row & 7)) << 3)] = *(const bf16x8*)vp;
    }
    __syncthreads();

    // QK^T
    float sv[4][4];
#pragma unroll
    for (int kb4 = 0; kb4 < 4; ++kb4) {
      f32x4 S = {0.f, 0.f, 0.f, 0.f};
      bf16x8 B0 = ldsf(Klds, (kb4 << 4) + l15, hi);
      bf16x8 B1 = ldsf(Klds, (kb4 << 4) + l15, 4 + hi);
      S = __builtin_amdgcn_mfma_f32_16x16x32_bf16(aQ0, B0, S, 0, 0, 0);
      S = __builtin_amdgcn_mfma_f32_16x16x32_bf16(aQ1, B1, S, 0, 0, 0);
      int key = (kt << 6) + (kb4 << 4) + l15;
#pragma unroll
      for (int r = 0; r < 4; ++r) {
        int qg = qrow0 + (hi << 2) + r;
        float val = S[r] * 0.125f;
        sv[kb4][r] = (key <= qg && key > qg - Wn) ? val : -INFINITY;
      }
    }

    // online softmax (4 independent chains)
    float scl[4], pv[4][4];
#pragma unroll
    for (int r = 0; r < 4; ++r) {
      float mt2 = fmaxf(fmaxf(sv[0][r], sv[1][r]), fmaxf(sv[2][r], sv[3][r]));
      mt2 = fmaxf(mt2, __shfl_xor(mt2, 1, 64));
      mt2 = fmaxf(mt2, __shfl_xor(mt2, 2, 64));
      mt2 = fmaxf(mt2, __shfl_xor(mt2, 4, 64));
      mt2 = fmaxf(mt2, __shfl_xor(mt2, 8, 64));
      float mn = fmaxf(mrow[r], mt2);
      float sc = (mrow[r] > -INFINITY) ? __expf(mrow[r] - mn) : 0.f;
      float rs = 0.f;
#pragma unroll
      for (int kb4 = 0; kb4 < 4; ++kb4) {
        float p = (sv[kb4][r] > -INFINITY) ? __expf(sv[kb4][r] - mn) : 0.f;
        pv[kb4][r] = p;
        rs += p;
      }
      rs += __shfl_xor(rs, 1, 64);
      rs += __shfl_xor(rs, 2, 64);
      rs += __shfl_xor(rs, 4, 64);
      rs += __shfl_xor(rs, 8, 64);
      mrow[r] = mn;
      lrow[r] = lrow[r] * sc + rs;
      scl[r] = sc;
    }

    // P -> wave-local swizzled LDS
#pragma unroll
    for (int kb4 = 0; kb4 < 4; ++kb4)
#pragma unroll
      for (int r = 0; r < 4; ++r) {
        int row16 = (hi << 2) + r;
        int seg = (kb4 << 1) + (l15 >> 3);
        Plds[wave][(row16 << 6) + ((seg ^ (row16 & 7)) << 3) + (l15 & 7)] = f2b(pv[kb4][r]);
      }
    // rescale O
#pragma unroll
    for (int df = 0; df < 4; ++df) {
      f32x4 t4 = o[df];
      t4[0] *= scl[0]; t4[1] *= scl[1]; t4[2] *= scl[2]; t4[3] *= scl[3];
      o[df] = t4;
    }
    // PV
#pragma unroll
    for (int ks = 0; ks < 2; ++ks) {
      bf16x8 Ap = ldsf(Plds[wave], l15, (ks << 2) + hi);
#pragma unroll
      for (int df = 0; df < 4; ++df) {
        bf16x8 Bv = ldsf(Vt, (df << 4) + l15, (ks << 2) + hi);
        o[df] = __builtin_amdgcn_mfma_f32_16x16x32_bf16(Ap, Bv, o[df], 0, 0, 0);
      }
    }
  }

  float inv[4];
#pragma unroll
  for (int r = 0; r < 4; ++r) inv[r] = lrow[r] > 0.f ? 1.f / lrow[r] : 0.f;
#pragma unroll
  for (int r = 0; r < 4; ++r) {
    size_t rbase = ((size_t)((b << 11) + qrow0 + (hi << 2) + r) << 10) + (h << 6) + l15;
#pragma unroll
    for (int df = 0; df < 4; ++df) {
      float fo = o[df][r] * inv[r];
      u16 hv = f2b(fo);
      yh[rbase + (df << 4)] = hv;
      yl[rbase + (df << 4)] = f2b(fo - b2f(hv));
    }
  }
}

// ---------------- top-2 router from precomputed logits ----------------
__global__ __launch_bounds__(256) void topk_k(const float* __restrict__ logits,
                                              const float* __restrict__ bias,
                                              int* __restrict__ topi,
                                              float* __restrict__ topw,
                                              int* __restrict__ counts) {
  int n = blockIdx.x * 256 + threadIdx.x;
  if (n >= NTOK) return;
  float sc[8], sel[8];
#pragma unroll
  for (int e2 = 0; e2 < 8; ++e2) {
    float sg = 1.f / (1.f + __expf(-logits[n * 8 + e2]));
    sc[e2] = sg;
    sel[e2] = sg + bias[e2];
  }
  int i1 = 0; float b1 = sel[0];
#pragma unroll
  for (int j = 1; j < 8; ++j) if (sel[j] > b1) { b1 = sel[j]; i1 = j; }
  int i2 = -1; float b2 = -INFINITY;
#pragma unroll
  for (int j = 0; j < 8; ++j) if (j != i1 && sel[j] > b2) { b2 = sel[j]; i2 = j; }
  float w1 = sc[i1], w2 = sc[i2];
  float invs = 1.f / (w1 + w2 + 1e-20f);
  topi[n * 2] = i1; topi[n * 2 + 1] = i2;
  topw[n * 2] = w1 * invs; topw[n * 2 + 1] = w2 * invs;
  atomicAdd(&counts[i1], 1);
  atomicAdd(&counts[i2], 1);
}

__global__ void scan_k(const int* __restrict__ counts, int* __restrict__ offsets) {
  if (threadIdx.x == 0 && blockIdx.x == 0) {
    int s = 0;
    for (int e2 = 0; e2 < 8; ++e2) { offsets[e2] = s; s += counts[e2]; }
    offsets[8] = s;
  }
}

__global__ __launch_bounds__(256) void scatter_k(const int* __restrict__ topi,
                                                 const float* __restrict__ topw,
                                                 const int* __restrict__ offsets,
                                                 int* __restrict__ counts2,
                                                 int* __restrict__ tok_idx,
                                                 float* __restrict__ tok_w) {
  int n = blockIdx.x * 256 + threadIdx.x;
  if (n >= NTOK) return;
  for (int kk = 0; kk < 2; ++kk) {
    int e2 = topi[n * 2 + kk];
    int slot = atomicAdd(&counts2[e2], 1);
    int p = offsets[e2] + slot;
    tok_idx[p] = n;
    tok_w[p] = topw[n * 2 + kk];
  }
}

extern "C" void kernel_launch(void* const* d_in, const int* in_sizes, int n_in,
                              void* d_out, int out_size, void* d_ws, size_t ws_size,
                              hipStream_t stream) {
  const float* x = (const float*)d_in[0];
  const float* ve = (const float*)d_in[1];
  const float* cosb = (const float*)d_in[2];
  const float* sinb = (const float*)d_in[3];
  const float* Wq = (const float*)d_in[4];
  const float* Wk = (const float*)d_in[5];
  const float* Wv = (const float*)d_in[6];
  const float* Wo = (const float*)d_in[7];
  const float* gW = (const float*)d_in[8];
  const float* routerW = (const float*)d_in[9];
  const float* bias = (const float*)d_in[10];
  const float* Wsfc = (const float*)d_in[11];
  const float* Wsproj = (const float*)d_in[12];
  const float* Wefc = (const float*)d_in[13];
  const float* Weproj = (const float*)d_in[14];
  const int* wsz = (const int*)d_in[15];
  float* out = (float*)d_out;
  char* WS = (char*)d_ws;

  // ---- workspace layout (byte offsets), peak ~90.7 MiB ----
  u16* Wefc_b   = (u16*)(WS + 0);          // 16 MiB
  u16* Weproj_b = (u16*)(WS + 16777216);   // 16 MiB
  u16* Wsfc_b   = (u16*)(WS + 33554432);   // 2 MiB
  u16* Wsproj_b = (u16*)(WS + 35651584);   // 2 MiB
  u16* Wq_hi    = (u16*)(WS + 37748736);   // 2 MiB
  u16* Wq_lo    = (u16*)(WS + 39845888);   // 2 MiB
  u16* Wk_hi    = (u16*)(WS + 41943040);   // 0.5 MiB
  u16* Wk_lo    = (u16*)(WS + 42467328);   // 0.5 MiB
  u16* Wv_hi    = (u16*)(WS + 42991616);   // 0.5 MiB
  u16* Wv_lo    = (u16*)(WS + 43515904);   // 0.5 MiB
  u16* Wo_hi    = (u16*)(WS + 44040192);   // 2 MiB
  u16* Wo_lo    = (u16*)(WS + 46137344);   // 2 MiB
  u16* h_hi     = (u16*)(WS + 48234496);   // 8 MiB [dead after QKV]
  u16* h_lo     = (u16*)(WS + 56623104);   // 8 MiB [dead after QKV]
  u16* qb       = (u16*)(WS + 65011712);   // 8 MiB [dead after attn]
  u16* kb       = (u16*)(WS + 73400320);   // 2 MiB [dead after attn]
  u16* vb       = (u16*)(WS + 75497472);   // 2 MiB [dead after attn] (transposed layout)
  u16* y_hi     = (u16*)(WS + 77594624);   // 8 MiB [dead after Wo gemm]
  u16* y_lo     = (u16*)(WS + 85983232);   // 8 MiB [dead after Wo gemm]
  float* x2     = (float*)(WS + 48234496); // 16 MiB over h_hi+h_lo [written post-attn]
  u16* h2_b     = (u16*)(WS + 65011712);   // 8 MiB over qb [written post-Wo]
  u16* s1_b     = (u16*)(WS + 77594624);   // 8 MiB over y_hi [written post-Wo]
  u16* he_b     = (u16*)(WS + 48234496);   // 16 MiB over x2 [written post-sproj]
  float* gates  = (float*)(WS + 94371840); // 64 KiB
  float* logits = (float*)(WS + 94437376); // 128 KiB
  int* meta     = (int*)(WS + 94568448);
  int* counts   = meta;
  int* counts2  = meta + 8;
  int* offsets  = meta + 16;
  int* topi     = meta + 32;
  float* topw   = (float*)(meta + 8224);
  int* tok_idx  = meta + 16416;
  float* tok_w  = (float*)(meta + 24608);

  hipMemsetAsync(counts, 0, 16 * sizeof(int), stream);

  // fused weight converts
  cvt_split4_k<<<dim3(512, 4), 256, 0, stream>>>(Wq, Wk, Wv, Wo,
      Wq_hi, Wq_lo, Wk_hi, Wk_lo, Wv_hi, Wv_lo, Wo_hi, Wo_lo);
  cvt4_k<<<dim3(4096, 4), 256, 0, stream>>>(Wsfc, Wsproj, Wefc, Weproj,
      Wsfc_b, Wsproj_b, Wefc_b, Weproj_b);

  // h = rmsnorm(x) split + fused gates
  rmsnorm_split_k<<<NTOK, 256, 0, stream>>>(x, h_hi, h_lo, gW, gates);
  // fused QKV split gemm (N=1536) with per-head epilogues (V stored transposed)
  gemm_bf_k<11><<<dim3(12, 32), 256, 0, stream>>>(
      h_hi, h_lo, Wq_hi, Wq_lo, Wk_hi, Wk_lo, Wv_hi, Wv_lo,
      nullptr, qb, kb, vb, nullptr, 1536, 1024,
      nullptr, nullptr, nullptr, nullptr, cosb, sinb, gates, ve);
  // attention -> split y
  attn_mfma_k<<<dim3(128, 4, 2), 256, 0, stream>>>(qb, kb, vb, y_hi, y_lo, wsz);
  // x2 = x + y @ Wo^T (split)
  gemm_bf_k<6><<<dim3(8, 32), 256, 0, stream>>>(
      y_hi, y_lo, Wo_hi, Wo_lo, nullptr, nullptr, nullptr, nullptr,
      x2, nullptr, nullptr, nullptr, x, 1024, 1024,
      nullptr, nullptr, nullptr, nullptr, nullptr, nullptr, nullptr, nullptr);
  // h2 = rmsnorm(x2) -> bf16 + fp32 router logits
  rmsnorm_logits_k<<<NTOK, 256, 0, stream>>>(x2, h2_b, routerW, logits);
  // shared expert
  gemm_bf_k<3><<<dim3(8, 32), 256, 0, stream>>>(
      h2_b, nullptr, Wsfc_b, nullptr, nullptr, nullptr, nullptr, nullptr,
      nullptr, s1_b, nullptr, nullptr, nullptr, 1024, 1024,
      nullptr, nullptr, nullptr, nullptr, nullptr, nullptr, nullptr, nullptr);
  gemm_bf_k<1><<<dim3(8, 32), 256, 0, stream>>>(
      s1_b, nullptr, Wsproj_b, nullptr, nullptr, nullptr, nullptr, nullptr,
      out, nullptr, nullptr, nullptr, x2, 1024, 1024,
      nullptr, nullptr, nullptr, nullptr, nullptr, nullptr, nullptr, nullptr);
  // router + bucketing
  topk_k<<<16, 256, 0, stream>>>(logits, bias, topi, topw, counts);
  scan_k<<<1, 64, 0, stream>>>(counts, offsets);
  scatter_k<<<16, 256, 0, stream>>>(topi, topw, offsets, counts2, tok_idx, tok_w);
  // routed experts
  gemm_bf_k<4><<<dim3(8, 32, 8), 256, 0, stream>>>(
      h2_b, nullptr, Wefc_b, nullptr, nullptr, nullptr, nullptr, nullptr,
      nullptr, he_b, nullptr, nullptr, nullptr, 1024, 1024,
      offsets, counts, tok_idx, nullptr, nullptr, nullptr, nullptr, nullptr);
  gemm_bf_k<5><<<dim3(8, 32, 8), 256, 0, stream>>>(
      he_b, nullptr, Weproj_b, nullptr, nullptr, nullptr, nullptr, nullptr,
      out, nullptr, nullptr, nullptr, nullptr, 1024, 1024,
      offsets, counts, tok_idx, tok_w, nullptr, nullptr, nullptr, nullptr);
}